// Round 1
// baseline (1749.213 us; speedup 1.0000x reference)
//
#include <hip/hip_runtime.h>
#include <math.h>

#define BB 2
#define SS 2048
#define DD 1024
#define EE 16
#define HDD 64
#define CAPP 1280
#define TOPKK 8

// ---------------------------------------------------------------------------
// K1: gating — logits = x @ w_gate + b_gate, softmax over E, top-8 mask, mg
// one wave per token, 4 tokens per 256-thread block
// ---------------------------------------------------------------------------
__global__ __launch_bounds__(256) void gate_kernel(const float* __restrict__ x,
        const float* __restrict__ wg, const float* __restrict__ bg,
        float* __restrict__ gate) {
    int token = blockIdx.x * 4 + (threadIdx.x >> 6);
    int lane = threadIdx.x & 63;
    const float* xr = x + (size_t)token * DD;
    float acc[EE];
#pragma unroll
    for (int e = 0; e < EE; ++e) acc[e] = 0.0f;
    for (int d = lane; d < DD; d += 64) {
        float xv = xr[d];
        const float4* wr = (const float4*)(wg + (size_t)d * EE);
        float4 w0 = wr[0], w1 = wr[1], w2 = wr[2], w3 = wr[3];
        acc[0]  = fmaf(xv, w0.x, acc[0]);  acc[1]  = fmaf(xv, w0.y, acc[1]);
        acc[2]  = fmaf(xv, w0.z, acc[2]);  acc[3]  = fmaf(xv, w0.w, acc[3]);
        acc[4]  = fmaf(xv, w1.x, acc[4]);  acc[5]  = fmaf(xv, w1.y, acc[5]);
        acc[6]  = fmaf(xv, w1.z, acc[6]);  acc[7]  = fmaf(xv, w1.w, acc[7]);
        acc[8]  = fmaf(xv, w2.x, acc[8]);  acc[9]  = fmaf(xv, w2.y, acc[9]);
        acc[10] = fmaf(xv, w2.z, acc[10]); acc[11] = fmaf(xv, w2.w, acc[11]);
        acc[12] = fmaf(xv, w3.x, acc[12]); acc[13] = fmaf(xv, w3.y, acc[13]);
        acc[14] = fmaf(xv, w3.z, acc[14]); acc[15] = fmaf(xv, w3.w, acc[15]);
    }
#pragma unroll
    for (int e = 0; e < EE; ++e) {
        float v = acc[e];
#pragma unroll
        for (int off = 32; off > 0; off >>= 1) v += __shfl_xor(v, off, 64);
        acc[e] = v + bg[e];
    }
    // softmax over 16 (replicated in every lane)
    float mx = acc[0];
#pragma unroll
    for (int e = 1; e < EE; ++e) mx = fmaxf(mx, acc[e]);
    float sum = 0.0f;
#pragma unroll
    for (int e = 0; e < EE; ++e) { acc[e] = expf(acc[e] - mx); sum += acc[e]; }
    float inv = 1.0f / sum;
#pragma unroll
    for (int e = 0; e < EE; ++e) acc[e] *= inv;
    if (lane == 0) {
#pragma unroll
        for (int e = 0; e < EE; ++e) {
            int rank = 0;
#pragma unroll
            for (int j = 0; j < EE; ++j)
                rank += (acc[j] > acc[e]) || (acc[j] == acc[e] && j < e);
            gate[(size_t)token * EE + e] = (rank < TOPKK) ? acc[e] : 0.0f;
        }
    }
}

// ---------------------------------------------------------------------------
// K2: route = mg / (mg.sum over batch + eps) * capacity   (in place)
// ---------------------------------------------------------------------------
__global__ void route_kernel(float* __restrict__ gate) {
    int i = blockIdx.x * blockDim.x + threadIdx.x;   // over S*E
    if (i >= SS * EE) return;
    float m0 = gate[i];
    float m1 = gate[SS * EE + i];
    float den = m0 + m1 + 1e-6f;
    gate[i]           = m0 / den * 2.0f;   // capacity = int(1.0*B) = 2
    gate[SS * EE + i] = m1 / den * 2.0f;
}

// ---------------------------------------------------------------------------
// K3: per (e,b): select top-CAP tokens (JAX tie-break), output ascending ids
// ---------------------------------------------------------------------------
__global__ __launch_bounds__(1024) void select_kernel(const float* __restrict__ gate,
        int* __restrict__ seq_ids, float* __restrict__ wgt) {
    __shared__ float vals[SS];
    __shared__ int wsum[16];
    int eb = blockIdx.x;
    int e = eb >> 1, b = eb & 1;
    int t = threadIdx.x;
    for (int s = t; s < SS; s += 1024)
        vals[s] = gate[((size_t)b * SS + s) * EE + e];
    __syncthreads();
    int i0 = t * 2;
    float v0 = vals[i0], v1 = vals[i0 + 1];
    int r0 = 0, r1 = 0;
    for (int j = 0; j < SS; ++j) {
        float vj = vals[j];
        r0 += (int)((vj > v0) | ((vj == v0) & (j < i0)));
        r1 += (int)((vj > v1) | ((vj == v1) & (j < i0 + 1)));
    }
    int s0 = (r0 < CAPP), s1 = (r1 < CAPP);
    int cnt = s0 + s1;
    int lane = t & 63, wid = t >> 6;
    int incl = cnt;
#pragma unroll
    for (int off = 1; off < 64; off <<= 1) {
        int n = __shfl_up(incl, off, 64);
        if (lane >= off) incl += n;
    }
    if (lane == 63) wsum[wid] = incl;
    __syncthreads();
    int base = 0;
    for (int w = 0; w < wid; ++w) base += wsum[w];
    int pos = base + incl - cnt;
    if (s0) { seq_ids[(size_t)eb * CAPP + pos] = i0;     wgt[(size_t)eb * CAPP + pos] = v0; ++pos; }
    if (s1) { seq_ids[(size_t)eb * CAPP + pos] = i0 + 1; wgt[(size_t)eb * CAPP + pos] = v1; }
}

// ---------------------------------------------------------------------------
// K4: q/k/v projection, gathered A rows. per (e,b): [1280x1024] @ [1024x192]
// grid (20, 3, 32), block 256, 64x64 tile, 4x4 per thread
// ---------------------------------------------------------------------------
__global__ __launch_bounds__(256) void proj_kernel(const float* __restrict__ x,
        const float* __restrict__ Wq, const float* __restrict__ Wkv,
        const int* __restrict__ seq_ids, float* __restrict__ qo,
        float* __restrict__ ko, float* __restrict__ vo) {
    __shared__ float As[16][68];
    __shared__ float Bs[16][68];
    __shared__ int sids[64];
    int eb = blockIdx.z;
    int e = eb >> 1, b = eb & 1;
    int m0 = blockIdx.x * 64;
    int nb = blockIdx.y;
    int t = threadIdx.x;
    if (t < 64) sids[t] = seq_ids[(size_t)eb * CAPP + m0 + t];
    int ty = t >> 4, tx = t & 15;
    int am = t >> 2, akq = t & 3;
    const float* wsrc = (nb == 0) ? (Wq + (size_t)e * DD * HDD)
                                  : (Wkv + (size_t)e * DD * 2 * HDD + (size_t)(nb - 1) * HDD);
    int ldw = (nb == 0) ? HDD : 2 * HDD;
    float acc[4][4] = {};
    __syncthreads();
    for (int k0 = 0; k0 < DD; k0 += 16) {
        float4 av = *(const float4*)(x + ((size_t)(b * SS + sids[am])) * DD + k0 + akq * 4);
        float4 bv = *(const float4*)(wsrc + (size_t)(k0 + ty) * ldw + tx * 4);
        As[akq * 4 + 0][am] = av.x; As[akq * 4 + 1][am] = av.y;
        As[akq * 4 + 2][am] = av.z; As[akq * 4 + 3][am] = av.w;
        *(float4*)&Bs[ty][tx * 4] = bv;
        __syncthreads();
#pragma unroll
        for (int kk = 0; kk < 16; ++kk) {
            float4 a4 = *(const float4*)&As[kk][ty * 4];
            float4 b4 = *(const float4*)&Bs[kk][tx * 4];
            float a[4] = {a4.x, a4.y, a4.z, a4.w};
            float bbv[4] = {b4.x, b4.y, b4.z, b4.w};
#pragma unroll
            for (int i = 0; i < 4; ++i)
#pragma unroll
                for (int j = 0; j < 4; ++j)
                    acc[i][j] = fmaf(a[i], bbv[j], acc[i][j]);
        }
        __syncthreads();
    }
    float* dst = (nb == 0) ? qo : ((nb == 1) ? ko : vo);
#pragma unroll
    for (int i = 0; i < 4; ++i) {
        float4 o = make_float4(acc[i][0], acc[i][1], acc[i][2], acc[i][3]);
        *(float4*)(dst + ((size_t)eb * CAPP + m0 + ty * 4 + i) * HDD + tx * 4) = o;
    }
}

// ---------------------------------------------------------------------------
// K5: RoPE on q and k (positions = original seq ids)
// ---------------------------------------------------------------------------
__global__ void rope_kernel(const int* __restrict__ seq_ids,
        float* __restrict__ qo, float* __restrict__ ko) {
    int idx = blockIdx.x * blockDim.x + threadIdx.x;   // E*B*CAP*32
    if (idx >= EE * BB * CAPP * 32) return;
    int h = idx & 31;
    int slot = idx >> 5;
    int p = seq_ids[slot];
    float inv_freq = 1.0f / powf(10000.0f, (float)h * (1.0f / 32.0f));
    float arg = (float)p * inv_freq;
    float s, c;
    sincosf(arg, &s, &c);
    float* qp = qo + (size_t)slot * HDD;
    float q0 = qp[h], q1 = qp[h + 32];
    qp[h]      = q0 * c - q1 * s;
    qp[h + 32] = q1 * c + q0 * s;
    float* kp = ko + (size_t)slot * HDD;
    float k0 = kp[h], k1 = kp[h + 32];
    kp[h]      = k0 * c - k1 * s;
    kp[h + 32] = k1 * c + k0 * s;
}

// ---------------------------------------------------------------------------
// K6: causal flash attention per (e,b). grid (20, 32), block 256
// Q-tile 64 x KV-tile 64, 4x4 per thread
// ---------------------------------------------------------------------------
__global__ __launch_bounds__(256) void attn_kernel(const float* __restrict__ qi,
        const float* __restrict__ ki, const float* __restrict__ vi,
        float* __restrict__ ctx) {
    __shared__ float Qs[64][68], Ks[64][68], Vs[64][68], Ps[64][68];
    int eb = blockIdx.y;
    int qrow0 = blockIdx.x * 64;
    int t = threadIdx.x, ty = t >> 4, tx = t & 15;
    const float* qb = qi + (size_t)eb * CAPP * HDD;
    const float* kb = ki + (size_t)eb * CAPP * HDD;
    const float* vb = vi + (size_t)eb * CAPP * HDD;
#pragma unroll
    for (int i = 0; i < 4; ++i) {
        int idx = t + i * 256; int r = idx >> 4, c = (idx & 15) * 4;
        *(float4*)&Qs[r][c] = *(const float4*)(qb + (size_t)(qrow0 + r) * HDD + c);
    }
    float m_run[4], l_run[4], O[4][4];
#pragma unroll
    for (int i = 0; i < 4; ++i) {
        m_run[i] = -INFINITY; l_run[i] = 0.0f;
#pragma unroll
        for (int j = 0; j < 4; ++j) O[i][j] = 0.0f;
    }
    int ntile = blockIdx.x + 1;
    for (int kt = 0; kt < ntile; ++kt) {
        int krow0 = kt * 64;
        __syncthreads();
#pragma unroll
        for (int i = 0; i < 4; ++i) {
            int idx = t + i * 256; int r = idx >> 4, c = (idx & 15) * 4;
            *(float4*)&Ks[r][c] = *(const float4*)(kb + (size_t)(krow0 + r) * HDD + c);
            *(float4*)&Vs[r][c] = *(const float4*)(vb + (size_t)(krow0 + r) * HDD + c);
        }
        __syncthreads();
        float sc[4][4] = {};
#pragma unroll
        for (int h = 0; h < HDD; h += 4) {
            float4 qa[4], ka[4];
#pragma unroll
            for (int i = 0; i < 4; ++i) qa[i] = *(const float4*)&Qs[ty * 4 + i][h];
#pragma unroll
            for (int j = 0; j < 4; ++j) ka[j] = *(const float4*)&Ks[tx * 4 + j][h];
#pragma unroll
            for (int i = 0; i < 4; ++i)
#pragma unroll
                for (int j = 0; j < 4; ++j) {
                    sc[i][j] = fmaf(qa[i].x, ka[j].x, sc[i][j]);
                    sc[i][j] = fmaf(qa[i].y, ka[j].y, sc[i][j]);
                    sc[i][j] = fmaf(qa[i].z, ka[j].z, sc[i][j]);
                    sc[i][j] = fmaf(qa[i].w, ka[j].w, sc[i][j]);
                }
        }
#pragma unroll
        for (int i = 0; i < 4; ++i)
#pragma unroll
            for (int j = 0; j < 4; ++j) {
                float val = sc[i][j] * 0.125f;
                if (krow0 + tx * 4 + j > qrow0 + ty * 4 + i) val = -INFINITY;
                sc[i][j] = val;
            }
#pragma unroll
        for (int i = 0; i < 4; ++i) {
            float tm = fmaxf(fmaxf(sc[i][0], sc[i][1]), fmaxf(sc[i][2], sc[i][3]));
#pragma unroll
            for (int off = 1; off < 16; off <<= 1) tm = fmaxf(tm, __shfl_xor(tm, off, 64));
            float mnew = fmaxf(m_run[i], tm);
            float p0 = expf(sc[i][0] - mnew), p1 = expf(sc[i][1] - mnew);
            float p2 = expf(sc[i][2] - mnew), p3 = expf(sc[i][3] - mnew);
            *(float4*)&Ps[ty * 4 + i][tx * 4] = make_float4(p0, p1, p2, p3);
            float rs = p0 + p1 + p2 + p3;
#pragma unroll
            for (int off = 1; off < 16; off <<= 1) rs += __shfl_xor(rs, off, 64);
            float fac = expf(m_run[i] - mnew);
            l_run[i] = l_run[i] * fac + rs;
            m_run[i] = mnew;
#pragma unroll
            for (int j = 0; j < 4; ++j) O[i][j] *= fac;
        }
        __syncthreads();
#pragma unroll
        for (int jj = 0; jj < 64; jj += 4) {
            float4 pa[4], va[4];
#pragma unroll
            for (int i = 0; i < 4; ++i) pa[i] = *(const float4*)&Ps[ty * 4 + i][jj];
#pragma unroll
            for (int r = 0; r < 4; ++r) va[r] = *(const float4*)&Vs[jj + r][tx * 4];
#pragma unroll
            for (int i = 0; i < 4; ++i) {
                O[i][0] = fmaf(pa[i].x, va[0].x, O[i][0]);
                O[i][1] = fmaf(pa[i].x, va[0].y, O[i][1]);
                O[i][2] = fmaf(pa[i].x, va[0].z, O[i][2]);
                O[i][3] = fmaf(pa[i].x, va[0].w, O[i][3]);
                O[i][0] = fmaf(pa[i].y, va[1].x, O[i][0]);
                O[i][1] = fmaf(pa[i].y, va[1].y, O[i][1]);
                O[i][2] = fmaf(pa[i].y, va[1].z, O[i][2]);
                O[i][3] = fmaf(pa[i].y, va[1].w, O[i][3]);
                O[i][0] = fmaf(pa[i].z, va[2].x, O[i][0]);
                O[i][1] = fmaf(pa[i].z, va[2].y, O[i][1]);
                O[i][2] = fmaf(pa[i].z, va[2].z, O[i][2]);
                O[i][3] = fmaf(pa[i].z, va[2].w, O[i][3]);
                O[i][0] = fmaf(pa[i].w, va[3].x, O[i][0]);
                O[i][1] = fmaf(pa[i].w, va[3].y, O[i][1]);
                O[i][2] = fmaf(pa[i].w, va[3].z, O[i][2]);
                O[i][3] = fmaf(pa[i].w, va[3].w, O[i][3]);
            }
        }
    }
#pragma unroll
    for (int i = 0; i < 4; ++i) {
        float invl = 1.0f / l_run[i];
        float4 o = make_float4(O[i][0] * invl, O[i][1] * invl, O[i][2] * invl, O[i][3] * invl);
        *(float4*)(ctx + ((size_t)eb * CAPP + qrow0 + ty * 4 + i) * HDD + tx * 4) = o;
    }
}

// ---------------------------------------------------------------------------
// K7: out = (ctx @ Wff + bff) * w ; atomic scatter-add into combined
// grid (10, 8, 32), block 256, 128x128 tile, K=64, 8x8 per thread
// ---------------------------------------------------------------------------
__global__ __launch_bounds__(256) void outproj_kernel(const float* __restrict__ ctx,
        const float* __restrict__ Wff, const float* __restrict__ bff,
        const int* __restrict__ seq_ids, const float* __restrict__ wgt,
        float* __restrict__ combined) {
    __shared__ float As[16][132];
    __shared__ float Bs[16][132];
    int eb = blockIdx.z;
    int e = eb >> 1, b = eb & 1;
    int m0 = blockIdx.x * 128;
    int n0 = blockIdx.y * 128;
    int t = threadIdx.x, ty = t >> 4, tx = t & 15;
    float acc[8][8] = {};
    const float* cb = ctx + (size_t)eb * CAPP * HDD;
    const float* wb = Wff + (size_t)e * HDD * DD;
    for (int k0 = 0; k0 < HDD; k0 += 16) {
        __syncthreads();
#pragma unroll
        for (int i = 0; i < 2; ++i) {
            int idx = t + i * 256; int r = idx >> 2, kq = (idx & 3) * 4;
            float4 av = *(const float4*)(cb + (size_t)(m0 + r) * HDD + k0 + kq);
            As[kq + 0][r] = av.x; As[kq + 1][r] = av.y;
            As[kq + 2][r] = av.z; As[kq + 3][r] = av.w;
        }
#pragma unroll
        for (int i = 0; i < 2; ++i) {
            int idx = t + i * 256; int kb = idx >> 5, c = (idx & 31) * 4;
            *(float4*)&Bs[kb][c] = *(const float4*)(wb + (size_t)(k0 + kb) * DD + n0 + c);
        }
        __syncthreads();
#pragma unroll
        for (int kk = 0; kk < 16; ++kk) {
            float a[8], bv[8];
            *(float4*)&a[0] = *(const float4*)&As[kk][ty * 8];
            *(float4*)&a[4] = *(const float4*)&As[kk][ty * 8 + 4];
            *(float4*)&bv[0] = *(const float4*)&Bs[kk][tx * 8];
            *(float4*)&bv[4] = *(const float4*)&Bs[kk][tx * 8 + 4];
#pragma unroll
            for (int i = 0; i < 8; ++i)
#pragma unroll
                for (int j = 0; j < 8; ++j)
                    acc[i][j] = fmaf(a[i], bv[j], acc[i][j]);
        }
    }
    float bvreg[8];
    *(float4*)&bvreg[0] = *(const float4*)(bff + n0 + tx * 8);
    *(float4*)&bvreg[4] = *(const float4*)(bff + n0 + tx * 8 + 4);
#pragma unroll
    for (int i = 0; i < 8; ++i) {
        int m = m0 + ty * 8 + i;
        float wv = wgt[(size_t)eb * CAPP + m];
        if (wv != 0.0f) {
            int token = b * SS + seq_ids[(size_t)eb * CAPP + m];
            float* crow = combined + (size_t)token * DD + n0 + tx * 8;
#pragma unroll
            for (int j = 0; j < 8; ++j)
                unsafeAtomicAdd(&crow[j], (acc[i][j] + bvreg[j]) * wv);
        }
    }
}

// ---------------------------------------------------------------------------
// K8: h = x + combined ; LayerNorm(D) -> out
// ---------------------------------------------------------------------------
__global__ __launch_bounds__(256) void ln_kernel(const float* __restrict__ x,
        const float* __restrict__ combined, const float* __restrict__ gamma,
        const float* __restrict__ beta, float* __restrict__ out) {
    __shared__ float rsum[4], rsq[4];
    int token = blockIdx.x;
    int t = threadIdx.x;
    const float4* xr = (const float4*)(x + (size_t)token * DD);
    const float4* cr = (const float4*)(combined + (size_t)token * DD);
    float4 xv = xr[t], cv = cr[t];
    float4 h = make_float4(xv.x + cv.x, xv.y + cv.y, xv.z + cv.z, xv.w + cv.w);
    float sum = h.x + h.y + h.z + h.w;
    float sq  = h.x * h.x + h.y * h.y + h.z * h.z + h.w * h.w;
    int lane = t & 63, wid = t >> 6;
#pragma unroll
    for (int off = 32; off > 0; off >>= 1) {
        sum += __shfl_xor(sum, off, 64);
        sq  += __shfl_xor(sq, off, 64);
    }
    if (lane == 0) { rsum[wid] = sum; rsq[wid] = sq; }
    __syncthreads();
    float ts = rsum[0] + rsum[1] + rsum[2] + rsum[3];
    float tq = rsq[0] + rsq[1] + rsq[2] + rsq[3];
    float mu = ts * (1.0f / DD);
    float var = tq * (1.0f / DD) - mu * mu;
    float inv = rsqrtf(var + 1e-5f);
    float4 g = ((const float4*)gamma)[t];
    float4 be = ((const float4*)beta)[t];
    float4 o;
    o.x = (h.x - mu) * inv * g.x + be.x;
    o.y = (h.y - mu) * inv * g.y + be.y;
    o.z = (h.z - mu) * inv * g.z + be.z;
    o.w = (h.w - mu) * inv * g.w + be.w;
    ((float4*)(out + (size_t)token * DD))[t] = o;
}

// ---------------------------------------------------------------------------
extern "C" void kernel_launch(void* const* d_in, const int* in_sizes, int n_in,
                              void* d_out, int out_size, void* d_ws, size_t ws_size,
                              hipStream_t stream) {
    const float* x        = (const float*)d_in[0];
    const float* w_gate   = (const float*)d_in[1];
    const float* b_gate   = (const float*)d_in[2];
    const float* Wq       = (const float*)d_in[3];
    const float* Wkv      = (const float*)d_in[4];
    const float* Wff      = (const float*)d_in[5];
    const float* bff      = (const float*)d_in[6];
    const float* ln_gamma = (const float*)d_in[7];
    const float* ln_beta  = (const float*)d_in[8];
    float* out = (float*)d_out;
    char* ws = (char*)d_ws;

    // workspace layout (bytes, all 256-aligned); total ~59.3 MB
    float* gate     = (float*)(ws + 0);          // B*S*E           = 262144 B
    int*   seq_ids  = (int*)  (ws + 262144);     // E*B*CAP ints    = 163840 B
    float* wgt      = (float*)(ws + 425984);     // E*B*CAP         = 163840 B
    float* qbuf     = (float*)(ws + 589824);     // E*B*CAP*HD      = 10485760 B
    float* kbuf     = (float*)(ws + 11075584);
    float* vbuf     = (float*)(ws + 21561344);
    float* ctx      = (float*)(ws + 32047104);
    float* combined = (float*)(ws + 42532864);   // B*S*D           = 16777216 B

    hipMemsetAsync(combined, 0, (size_t)BB * SS * DD * sizeof(float), stream);

    gate_kernel<<<BB * SS / 4, 256, 0, stream>>>(x, w_gate, b_gate, gate);
    route_kernel<<<(SS * EE + 255) / 256, 256, 0, stream>>>(gate);
    select_kernel<<<EE * BB, 1024, 0, stream>>>(gate, seq_ids, wgt);
    proj_kernel<<<dim3(CAPP / 64, 3, EE * BB), 256, 0, stream>>>(x, Wq, Wkv, seq_ids,
                                                                 qbuf, kbuf, vbuf);
    rope_kernel<<<(EE * BB * CAPP * 32) / 256, 256, 0, stream>>>(seq_ids, qbuf, kbuf);
    attn_kernel<<<dim3(CAPP / 64, EE * BB), 256, 0, stream>>>(qbuf, kbuf, vbuf, ctx);
    outproj_kernel<<<dim3(CAPP / 128, DD / 128, EE * BB), 256, 0, stream>>>(
        ctx, Wff, bff, seq_ids, wgt, combined);
    ln_kernel<<<BB * SS, 256, 0, stream>>>(x, combined, ln_gamma, ln_beta, out);
}

// Round 3
// 968.563 us; speedup vs baseline: 1.8060x; 1.8060x over previous
//
#include <hip/hip_runtime.h>
#include <math.h>

#define BB 2
#define SS 2048
#define DD 1024
#define EE 16
#define HDD 64
#define CAPP 1280
#define TOPKK 8

// ---------------------------------------------------------------------------
// K1: gating — logits = x @ w_gate + b_gate, softmax over E, top-8 mask, mg
// ---------------------------------------------------------------------------
__global__ __launch_bounds__(256) void gate_kernel(const float* __restrict__ x,
        const float* __restrict__ wg, const float* __restrict__ bg,
        float* __restrict__ gate) {
    int token = blockIdx.x * 4 + (threadIdx.x >> 6);
    int lane = threadIdx.x & 63;
    const float* xr = x + (size_t)token * DD;
    float acc[EE];
#pragma unroll
    for (int e = 0; e < EE; ++e) acc[e] = 0.0f;
    for (int d = lane; d < DD; d += 64) {
        float xv = xr[d];
        const float4* wr = (const float4*)(wg + (size_t)d * EE);
        float4 w0 = wr[0], w1 = wr[1], w2 = wr[2], w3 = wr[3];
        acc[0]  = fmaf(xv, w0.x, acc[0]);  acc[1]  = fmaf(xv, w0.y, acc[1]);
        acc[2]  = fmaf(xv, w0.z, acc[2]);  acc[3]  = fmaf(xv, w0.w, acc[3]);
        acc[4]  = fmaf(xv, w1.x, acc[4]);  acc[5]  = fmaf(xv, w1.y, acc[5]);
        acc[6]  = fmaf(xv, w1.z, acc[6]);  acc[7]  = fmaf(xv, w1.w, acc[7]);
        acc[8]  = fmaf(xv, w2.x, acc[8]);  acc[9]  = fmaf(xv, w2.y, acc[9]);
        acc[10] = fmaf(xv, w2.z, acc[10]); acc[11] = fmaf(xv, w2.w, acc[11]);
        acc[12] = fmaf(xv, w3.x, acc[12]); acc[13] = fmaf(xv, w3.y, acc[13]);
        acc[14] = fmaf(xv, w3.z, acc[14]); acc[15] = fmaf(xv, w3.w, acc[15]);
    }
#pragma unroll
    for (int e = 0; e < EE; ++e) {
        float v = acc[e];
#pragma unroll
        for (int off = 32; off > 0; off >>= 1) v += __shfl_xor(v, off, 64);
        acc[e] = v + bg[e];
    }
    float mx = acc[0];
#pragma unroll
    for (int e = 1; e < EE; ++e) mx = fmaxf(mx, acc[e]);
    float sum = 0.0f;
#pragma unroll
    for (int e = 0; e < EE; ++e) { acc[e] = expf(acc[e] - mx); sum += acc[e]; }
    float inv = 1.0f / sum;
#pragma unroll
    for (int e = 0; e < EE; ++e) acc[e] *= inv;
    if (lane == 0) {
#pragma unroll
        for (int e = 0; e < EE; ++e) {
            int rank = 0;
#pragma unroll
            for (int j = 0; j < EE; ++j)
                rank += (acc[j] > acc[e]) || (acc[j] == acc[e] && j < e);
            gate[(size_t)token * EE + e] = (rank < TOPKK) ? acc[e] : 0.0f;
        }
    }
}

// ---------------------------------------------------------------------------
// K2: route = mg / (mg.sum over batch + eps) * capacity   (in place)
// ---------------------------------------------------------------------------
__global__ void route_kernel(float* __restrict__ gate) {
    int i = blockIdx.x * blockDim.x + threadIdx.x;
    if (i >= SS * EE) return;
    float m0 = gate[i];
    float m1 = gate[SS * EE + i];
    float den = m0 + m1 + 1e-6f;
    gate[i]           = m0 / den * 2.0f;
    gate[SS * EE + i] = m1 / den * 2.0f;
}

// ---------------------------------------------------------------------------
// K3: per (e,b): select top-CAP tokens (JAX tie-break), ascending ids.
// Also writes inverse map inv_slot[token][e] = slot (pre-memset to -1).
// ---------------------------------------------------------------------------
__global__ __launch_bounds__(1024) void select_kernel(const float* __restrict__ gate,
        int* __restrict__ seq_ids, int* __restrict__ inv_slot) {
    __shared__ float vals[SS];
    __shared__ int wsum[16];
    int eb = blockIdx.x;
    int e = eb >> 1, b = eb & 1;
    int t = threadIdx.x;
    for (int s = t; s < SS; s += 1024)
        vals[s] = gate[((size_t)b * SS + s) * EE + e];
    __syncthreads();
    int i0 = t * 2;
    float v0 = vals[i0], v1 = vals[i0 + 1];
    int r0 = 0, r1 = 0;
    for (int j = 0; j < SS; ++j) {
        float vj = vals[j];
        r0 += (int)((vj > v0) | ((vj == v0) & (j < i0)));
        r1 += (int)((vj > v1) | ((vj == v1) & (j < i0 + 1)));
    }
    int s0 = (r0 < CAPP), s1 = (r1 < CAPP);
    int cnt = s0 + s1;
    int lane = t & 63, wid = t >> 6;
    int incl = cnt;
#pragma unroll
    for (int off = 1; off < 64; off <<= 1) {
        int n = __shfl_up(incl, off, 64);
        if (lane >= off) incl += n;
    }
    if (lane == 63) wsum[wid] = incl;
    __syncthreads();
    int base = 0;
    for (int w = 0; w < wid; ++w) base += wsum[w];
    int pos = base + incl - cnt;
    if (s0) {
        seq_ids[(size_t)eb * CAPP + pos] = i0;
        inv_slot[((size_t)b * SS + i0) * EE + e] = pos;
        ++pos;
    }
    if (s1) {
        seq_ids[(size_t)eb * CAPP + pos] = i0 + 1;
        inv_slot[((size_t)b * SS + i0 + 1) * EE + e] = pos;
    }
}

// ---------------------------------------------------------------------------
// K4: q/k/v projection (gathered rows) with RoPE fused into the epilogue for
// q (nb==0) and k (nb==1). grid (20, 3, 32), block 256.
// ---------------------------------------------------------------------------
__global__ __launch_bounds__(256) void proj_kernel(const float* __restrict__ x,
        const float* __restrict__ Wq, const float* __restrict__ Wkv,
        const int* __restrict__ seq_ids, float* __restrict__ qo,
        float* __restrict__ ko, float* __restrict__ vo) {
    __shared__ float As[16][68];
    __shared__ float Bs[16][68];
    __shared__ int sids[64];
    int eb = blockIdx.z;
    int e = eb >> 1, b = eb & 1;
    int m0 = blockIdx.x * 64;
    int nb = blockIdx.y;
    int t = threadIdx.x;
    if (t < 64) sids[t] = seq_ids[(size_t)eb * CAPP + m0 + t];
    int ty = t >> 4, tx = t & 15;
    int am = t >> 2, akq = t & 3;
    const float* wsrc = (nb == 0) ? (Wq + (size_t)e * DD * HDD)
                                  : (Wkv + (size_t)e * DD * 2 * HDD + (size_t)(nb - 1) * HDD);
    int ldw = (nb == 0) ? HDD : 2 * HDD;
    float acc[4][4] = {};
    __syncthreads();
    for (int k0 = 0; k0 < DD; k0 += 16) {
        float4 av = *(const float4*)(x + ((size_t)(b * SS + sids[am])) * DD + k0 + akq * 4);
        float4 bv = *(const float4*)(wsrc + (size_t)(k0 + ty) * ldw + tx * 4);
        As[akq * 4 + 0][am] = av.x; As[akq * 4 + 1][am] = av.y;
        As[akq * 4 + 2][am] = av.z; As[akq * 4 + 3][am] = av.w;
        *(float4*)&Bs[ty][tx * 4] = bv;
        __syncthreads();
#pragma unroll
        for (int kk = 0; kk < 16; ++kk) {
            float4 a4 = *(const float4*)&As[kk][ty * 4];
            float4 b4 = *(const float4*)&Bs[kk][tx * 4];
            float a[4] = {a4.x, a4.y, a4.z, a4.w};
            float bbv[4] = {b4.x, b4.y, b4.z, b4.w};
#pragma unroll
            for (int i = 0; i < 4; ++i)
#pragma unroll
                for (int j = 0; j < 4; ++j)
                    acc[i][j] = fmaf(a[i], bbv[j], acc[i][j]);
        }
        __syncthreads();
    }
    float* dst = (nb == 0) ? qo : ((nb == 1) ? ko : vo);
    if (nb == 2) {
#pragma unroll
        for (int i = 0; i < 4; ++i) {
            float4 o = make_float4(acc[i][0], acc[i][1], acc[i][2], acc[i][3]);
            *(float4*)(dst + ((size_t)eb * CAPP + m0 + ty * 4 + i) * HDD + tx * 4) = o;
        }
    } else {
        // RoPE: col = tx*4+jj, partner col = col^32 lives at lane tx^8 (same jj)
        float sgn = (tx < 8) ? -1.0f : 1.0f;
#pragma unroll
        for (int i = 0; i < 4; ++i) {
            float p = (float)sids[ty * 4 + i];
            float o[4];
#pragma unroll
            for (int jj = 0; jj < 4; ++jj) {
                float prt = __shfl_xor(acc[i][jj], 8, 64);
                int j = (tx & 7) * 4 + jj;                 // col & 31
                float ang = p * exp2f((float)j * -0.41524101186092029f);
                float s, c;
                sincosf(ang, &s, &c);
                o[jj] = acc[i][jj] * c + sgn * prt * s;
            }
            *(float4*)(dst + ((size_t)eb * CAPP + m0 + ty * 4 + i) * HDD + tx * 4) =
                make_float4(o[0], o[1], o[2], o[3]);
        }
    }
}

// ---------------------------------------------------------------------------
// K6: causal flash attention per (e,b). grid (20, 32), block 256.
// K-tile stored with XOR swizzle col^(row&28) -> conflict-free QK reads.
// Reverse q-tile order (big tiles dispatched first) for tail balance.
// ---------------------------------------------------------------------------
__global__ __launch_bounds__(256) void attn_kernel(const float* __restrict__ qi,
        const float* __restrict__ ki, const float* __restrict__ vi,
        float* __restrict__ ctx) {
    __shared__ float Qs[64][68], Ks[64][68], Vs[64][68], Ps[64][68];
    int eb = blockIdx.y;
    int qt = (gridDim.x - 1) - blockIdx.x;         // descending work order
    int qrow0 = qt * 64;
    int t = threadIdx.x, ty = t >> 4, tx = t & 15;
    const float* qb = qi + (size_t)eb * CAPP * HDD;
    const float* kb = ki + (size_t)eb * CAPP * HDD;
    const float* vb = vi + (size_t)eb * CAPP * HDD;
#pragma unroll
    for (int i = 0; i < 4; ++i) {
        int idx = t + i * 256; int r = idx >> 4, c = (idx & 15) * 4;
        *(float4*)&Qs[r][c] = *(const float4*)(qb + (size_t)(qrow0 + r) * HDD + c);
    }
    float m_run[4], l_run[4], O[4][4];
#pragma unroll
    for (int i = 0; i < 4; ++i) {
        m_run[i] = -INFINITY; l_run[i] = 0.0f;
#pragma unroll
        for (int j = 0; j < 4; ++j) O[i][j] = 0.0f;
    }
    int ntile = qt + 1;
    for (int kt = 0; kt < ntile; ++kt) {
        int krow0 = kt * 64;
        __syncthreads();
#pragma unroll
        for (int i = 0; i < 4; ++i) {
            int idx = t + i * 256; int r = idx >> 4, c = (idx & 15) * 4;
            *(float4*)&Ks[r][c ^ (r & 28)] =
                *(const float4*)(kb + (size_t)(krow0 + r) * HDD + c);
            *(float4*)&Vs[r][c] = *(const float4*)(vb + (size_t)(krow0 + r) * HDD + c);
        }
        __syncthreads();
        float sc[4][4] = {};
#pragma unroll
        for (int h = 0; h < HDD; h += 4) {
            float4 qa[4], ka[4];
#pragma unroll
            for (int i = 0; i < 4; ++i) qa[i] = *(const float4*)&Qs[ty * 4 + i][h];
#pragma unroll
            for (int j = 0; j < 4; ++j) {
                int kr = tx * 4 + j;
                ka[j] = *(const float4*)&Ks[kr][h ^ (kr & 28)];
            }
#pragma unroll
            for (int i = 0; i < 4; ++i)
#pragma unroll
                for (int j = 0; j < 4; ++j) {
                    sc[i][j] = fmaf(qa[i].x, ka[j].x, sc[i][j]);
                    sc[i][j] = fmaf(qa[i].y, ka[j].y, sc[i][j]);
                    sc[i][j] = fmaf(qa[i].z, ka[j].z, sc[i][j]);
                    sc[i][j] = fmaf(qa[i].w, ka[j].w, sc[i][j]);
                }
        }
        if (kt == qt) {                            // only diagonal tile masks
#pragma unroll
            for (int i = 0; i < 4; ++i)
#pragma unroll
                for (int j = 0; j < 4; ++j) {
                    float val = sc[i][j] * 0.125f;
                    if (krow0 + tx * 4 + j > qrow0 + ty * 4 + i) val = -INFINITY;
                    sc[i][j] = val;
                }
        } else {
#pragma unroll
            for (int i = 0; i < 4; ++i)
#pragma unroll
                for (int j = 0; j < 4; ++j) sc[i][j] *= 0.125f;
        }
#pragma unroll
        for (int i = 0; i < 4; ++i) {
            float tm = fmaxf(fmaxf(sc[i][0], sc[i][1]), fmaxf(sc[i][2], sc[i][3]));
#pragma unroll
            for (int off = 1; off < 16; off <<= 1) tm = fmaxf(tm, __shfl_xor(tm, off, 64));
            float mnew = fmaxf(m_run[i], tm);
            float p0 = expf(sc[i][0] - mnew), p1 = expf(sc[i][1] - mnew);
            float p2 = expf(sc[i][2] - mnew), p3 = expf(sc[i][3] - mnew);
            *(float4*)&Ps[ty * 4 + i][tx * 4] = make_float4(p0, p1, p2, p3);
            float rs = p0 + p1 + p2 + p3;
#pragma unroll
            for (int off = 1; off < 16; off <<= 1) rs += __shfl_xor(rs, off, 64);
            float fac = expf(m_run[i] - mnew);
            l_run[i] = l_run[i] * fac + rs;
            m_run[i] = mnew;
#pragma unroll
            for (int j = 0; j < 4; ++j) O[i][j] *= fac;
        }
        __syncthreads();
#pragma unroll
        for (int jj = 0; jj < 64; jj += 4) {
            float4 pa[4], va[4];
#pragma unroll
            for (int i = 0; i < 4; ++i) pa[i] = *(const float4*)&Ps[ty * 4 + i][jj];
#pragma unroll
            for (int r = 0; r < 4; ++r) va[r] = *(const float4*)&Vs[jj + r][tx * 4];
#pragma unroll
            for (int i = 0; i < 4; ++i) {
                O[i][0] = fmaf(pa[i].x, va[0].x, O[i][0]);
                O[i][1] = fmaf(pa[i].x, va[0].y, O[i][1]);
                O[i][2] = fmaf(pa[i].x, va[0].z, O[i][2]);
                O[i][3] = fmaf(pa[i].x, va[0].w, O[i][3]);
                O[i][0] = fmaf(pa[i].y, va[1].x, O[i][0]);
                O[i][1] = fmaf(pa[i].y, va[1].y, O[i][1]);
                O[i][2] = fmaf(pa[i].y, va[1].z, O[i][2]);
                O[i][3] = fmaf(pa[i].y, va[1].w, O[i][3]);
                O[i][0] = fmaf(pa[i].z, va[2].x, O[i][0]);
                O[i][1] = fmaf(pa[i].z, va[2].y, O[i][1]);
                O[i][2] = fmaf(pa[i].z, va[2].z, O[i][2]);
                O[i][3] = fmaf(pa[i].z, va[2].w, O[i][3]);
                O[i][0] = fmaf(pa[i].w, va[3].x, O[i][0]);
                O[i][1] = fmaf(pa[i].w, va[3].y, O[i][1]);
                O[i][2] = fmaf(pa[i].w, va[3].z, O[i][2]);
                O[i][3] = fmaf(pa[i].w, va[3].w, O[i][3]);
            }
        }
    }
#pragma unroll
    for (int i = 0; i < 4; ++i) {
        float invl = 1.0f / l_run[i];
        float4 o = make_float4(O[i][0] * invl, O[i][1] * invl, O[i][2] * invl, O[i][3] * invl);
        *(float4*)(ctx + ((size_t)eb * CAPP + qrow0 + ty * 4 + i) * HDD + tx * 4) = o;
    }
}

// ---------------------------------------------------------------------------
// K7: token-major combine — NO atomics. grid (B*S/64, D/128), block 256.
// combined[token][d] = sum_e w_e*(ctx[e,b,slot]·Wff[e][:,d]) + (sum_e w_e)*bff[d]
// ---------------------------------------------------------------------------
__global__ __launch_bounds__(256) void combine_kernel(const float* __restrict__ ctx,
        const float* __restrict__ Wff, const float* __restrict__ bff,
        const int* __restrict__ inv_slot, const float* __restrict__ gate,
        float* __restrict__ combined) {
    __shared__ float AsT[64][68];      // [k][token-row], weighted
    __shared__ float Bs[64][132];      // [k][n]
    __shared__ int slotL[64];
    __shared__ float wL[64];
    int tb = blockIdx.x * 64;          // flat token base (same b within tile)
    int b = tb / SS;
    int n0 = blockIdx.y * 128;
    int t = threadIdx.x;
    int ty = t >> 5, tx = t & 31;      // 8 x 32 -> each thread 8 rows x 4 cols
    float acc[8][4] = {};
    float wsum[8] = {};
    for (int e = 0; e < EE; ++e) {
        __syncthreads();
        if (t < 64) {
            int slot = inv_slot[(size_t)(tb + t) * EE + e];
            slotL[t] = slot;
            wL[t] = (slot >= 0) ? gate[(size_t)(tb + t) * EE + e] : 0.0f;
        }
        __syncthreads();
        const float* cb = ctx + ((size_t)(e * BB + b)) * CAPP * HDD;
#pragma unroll
        for (int i = 0; i < 4; ++i) {
            int idx = t + i * 256;              // 0..1023
            int r = idx >> 4, c4 = (idx & 15) * 4;
            int slot = slotL[r];
            float w = wL[r];
            float4 v = make_float4(0.f, 0.f, 0.f, 0.f);
            if (slot >= 0 && w != 0.0f)
                v = *(const float4*)(cb + (size_t)slot * HDD + c4);
            AsT[c4 + 0][r] = v.x * w; AsT[c4 + 1][r] = v.y * w;
            AsT[c4 + 2][r] = v.z * w; AsT[c4 + 3][r] = v.w * w;
        }
        const float* wb = Wff + (size_t)e * HDD * DD + n0;
#pragma unroll
        for (int i = 0; i < 8; ++i) {
            int idx = t + i * 256;              // 0..2047
            int r = idx >> 5, c4 = (idx & 31) * 4;
            *(float4*)&Bs[r][c4] = *(const float4*)(wb + (size_t)r * DD + c4);
        }
        __syncthreads();
#pragma unroll 8
        for (int kk = 0; kk < 64; ++kk) {
            float4 b4 = *(const float4*)&Bs[kk][tx * 4];
            float4 a0 = *(const float4*)&AsT[kk][ty * 8];
            float4 a1 = *(const float4*)&AsT[kk][ty * 8 + 4];
            float a[8] = {a0.x, a0.y, a0.z, a0.w, a1.x, a1.y, a1.z, a1.w};
#pragma unroll
            for (int i = 0; i < 8; ++i) {
                acc[i][0] = fmaf(a[i], b4.x, acc[i][0]);
                acc[i][1] = fmaf(a[i], b4.y, acc[i][1]);
                acc[i][2] = fmaf(a[i], b4.z, acc[i][2]);
                acc[i][3] = fmaf(a[i], b4.w, acc[i][3]);
            }
        }
#pragma unroll
        for (int i = 0; i < 8; ++i) wsum[i] += wL[ty * 8 + i];
    }
    float4 bf = *(const float4*)(bff + n0 + tx * 4);
#pragma unroll
    for (int i = 0; i < 8; ++i) {
        int token = tb + ty * 8 + i;
        float4 o = make_float4(acc[i][0] + wsum[i] * bf.x,
                               acc[i][1] + wsum[i] * bf.y,
                               acc[i][2] + wsum[i] * bf.z,
                               acc[i][3] + wsum[i] * bf.w);
        *(float4*)(combined + (size_t)token * DD + n0 + tx * 4) = o;
    }
}

// ---------------------------------------------------------------------------
// K8: h = x + combined ; LayerNorm(D) -> out
// ---------------------------------------------------------------------------
__global__ __launch_bounds__(256) void ln_kernel(const float* __restrict__ x,
        const float* __restrict__ combined, const float* __restrict__ gamma,
        const float* __restrict__ beta, float* __restrict__ out) {
    __shared__ float rsum[4], rsq[4];
    int token = blockIdx.x;
    int t = threadIdx.x;
    const float4* xr = (const float4*)(x + (size_t)token * DD);
    const float4* cr = (const float4*)(combined + (size_t)token * DD);
    float4 xv = xr[t], cv = cr[t];
    float4 h = make_float4(xv.x + cv.x, xv.y + cv.y, xv.z + cv.z, xv.w + cv.w);
    float sum = h.x + h.y + h.z + h.w;
    float sq  = h.x * h.x + h.y * h.y + h.z * h.z + h.w * h.w;
    int lane = t & 63, wid = t >> 6;
#pragma unroll
    for (int off = 32; off > 0; off >>= 1) {
        sum += __shfl_xor(sum, off, 64);
        sq  += __shfl_xor(sq, off, 64);
    }
    if (lane == 0) { rsum[wid] = sum; rsq[wid] = sq; }
    __syncthreads();
    float ts = rsum[0] + rsum[1] + rsum[2] + rsum[3];
    float tq = rsq[0] + rsq[1] + rsq[2] + rsq[3];
    float mu = ts * (1.0f / DD);
    float var = tq * (1.0f / DD) - mu * mu;
    float inv = rsqrtf(var + 1e-5f);
    float4 g = ((const float4*)gamma)[t];
    float4 be = ((const float4*)beta)[t];
    float4 o;
    o.x = (h.x - mu) * inv * g.x + be.x;
    o.y = (h.y - mu) * inv * g.y + be.y;
    o.z = (h.z - mu) * inv * g.z + be.z;
    o.w = (h.w - mu) * inv * g.w + be.w;
    ((float4*)(out + (size_t)token * DD))[t] = o;
}

// ---------------------------------------------------------------------------
extern "C" void kernel_launch(void* const* d_in, const int* in_sizes, int n_in,
                              void* d_out, int out_size, void* d_ws, size_t ws_size,
                              hipStream_t stream) {
    const float* x        = (const float*)d_in[0];
    const float* w_gate   = (const float*)d_in[1];
    const float* b_gate   = (const float*)d_in[2];
    const float* Wq       = (const float*)d_in[3];
    const float* Wkv      = (const float*)d_in[4];
    const float* Wff      = (const float*)d_in[5];
    const float* bff      = (const float*)d_in[6];
    const float* ln_gamma = (const float*)d_in[7];
    const float* ln_beta  = (const float*)d_in[8];
    float* out = (float*)d_out;
    char* ws = (char*)d_ws;

    // workspace layout (bytes); total ~59.4 MB
    float* gate     = (float*)(ws + 0);           // B*S*E            262144
    int*   seq_ids  = (int*)  (ws + 262144);      // E*B*CAP          163840
    int*   inv_slot = (int*)  (ws + 425984);      // B*S*E            262144
    float* qbuf     = (float*)(ws + 688128);      // E*B*CAP*HD       10485760
    float* kbuf     = (float*)(ws + 11173888);
    float* vbuf     = (float*)(ws + 21659648);
    float* ctx      = (float*)(ws + 32145408);
    float* combined = (float*)(ws + 42631168);    // B*S*D            16777216

    hipMemsetAsync(inv_slot, 0xFF, (size_t)BB * SS * EE * sizeof(int), stream);

    gate_kernel<<<BB * SS / 4, 256, 0, stream>>>(x, w_gate, b_gate, gate);
    route_kernel<<<(SS * EE + 255) / 256, 256, 0, stream>>>(gate);
    select_kernel<<<EE * BB, 1024, 0, stream>>>(gate, seq_ids, inv_slot);
    proj_kernel<<<dim3(CAPP / 64, 3, EE * BB), 256, 0, stream>>>(x, Wq, Wkv, seq_ids,
                                                                 qbuf, kbuf, vbuf);
    attn_kernel<<<dim3(CAPP / 64, EE * BB), 256, 0, stream>>>(qbuf, kbuf, vbuf, ctx);
    combine_kernel<<<dim3(BB * SS / 64, DD / 128), 256, 0, stream>>>(
        ctx, Wff, bff, inv_slot, gate, combined);
    ln_kernel<<<BB * SS, 256, 0, stream>>>(x, combined, ln_gamma, ln_beta, out);
}

// Round 4
// 687.585 us; speedup vs baseline: 2.5440x; 1.4086x over previous
//
#include <hip/hip_runtime.h>
#include <math.h>

#define BB 2
#define SS 2048
#define DD 1024
#define EE 16
#define HDD 64
#define CAPP 1280
#define TOPKK 8

typedef __attribute__((ext_vector_type(8))) short bf16x8;
typedef __attribute__((ext_vector_type(4))) float f32x4;

static __device__ __forceinline__ unsigned short f2b(float f) {
    union { float f; unsigned u; } v; v.f = f;
    unsigned r = v.u + 0x7FFF + ((v.u >> 16) & 1);   // RNE
    return (unsigned short)(r >> 16);
}

// ---------------------------------------------------------------------------
// K1: gating — logits = x @ w_gate + b_gate, softmax over E, top-8 mask, mg
// ---------------------------------------------------------------------------
__global__ __launch_bounds__(256) void gate_kernel(const float* __restrict__ x,
        const float* __restrict__ wg, const float* __restrict__ bg,
        float* __restrict__ gate) {
    int token = blockIdx.x * 4 + (threadIdx.x >> 6);
    int lane = threadIdx.x & 63;
    const float* xr = x + (size_t)token * DD;
    float acc[EE];
#pragma unroll
    for (int e = 0; e < EE; ++e) acc[e] = 0.0f;
    for (int d = lane; d < DD; d += 64) {
        float xv = xr[d];
        const float4* wr = (const float4*)(wg + (size_t)d * EE);
        float4 w0 = wr[0], w1 = wr[1], w2 = wr[2], w3 = wr[3];
        acc[0]  = fmaf(xv, w0.x, acc[0]);  acc[1]  = fmaf(xv, w0.y, acc[1]);
        acc[2]  = fmaf(xv, w0.z, acc[2]);  acc[3]  = fmaf(xv, w0.w, acc[3]);
        acc[4]  = fmaf(xv, w1.x, acc[4]);  acc[5]  = fmaf(xv, w1.y, acc[5]);
        acc[6]  = fmaf(xv, w1.z, acc[6]);  acc[7]  = fmaf(xv, w1.w, acc[7]);
        acc[8]  = fmaf(xv, w2.x, acc[8]);  acc[9]  = fmaf(xv, w2.y, acc[9]);
        acc[10] = fmaf(xv, w2.z, acc[10]); acc[11] = fmaf(xv, w2.w, acc[11]);
        acc[12] = fmaf(xv, w3.x, acc[12]); acc[13] = fmaf(xv, w3.y, acc[13]);
        acc[14] = fmaf(xv, w3.z, acc[14]); acc[15] = fmaf(xv, w3.w, acc[15]);
    }
#pragma unroll
    for (int e = 0; e < EE; ++e) {
        float v = acc[e];
#pragma unroll
        for (int off = 32; off > 0; off >>= 1) v += __shfl_xor(v, off, 64);
        acc[e] = v + bg[e];
    }
    float mx = acc[0];
#pragma unroll
    for (int e = 1; e < EE; ++e) mx = fmaxf(mx, acc[e]);
    float sum = 0.0f;
#pragma unroll
    for (int e = 0; e < EE; ++e) { acc[e] = expf(acc[e] - mx); sum += acc[e]; }
    float inv = 1.0f / sum;
#pragma unroll
    for (int e = 0; e < EE; ++e) acc[e] *= inv;
    if (lane == 0) {
#pragma unroll
        for (int e = 0; e < EE; ++e) {
            int rank = 0;
#pragma unroll
            for (int j = 0; j < EE; ++j)
                rank += (acc[j] > acc[e]) || (acc[j] == acc[e] && j < e);
            gate[(size_t)token * EE + e] = (rank < TOPKK) ? acc[e] : 0.0f;
        }
    }
}

// ---------------------------------------------------------------------------
// K2: route = mg / (mg.sum over batch + eps) * capacity   (in place)
// ---------------------------------------------------------------------------
__global__ void route_kernel(float* __restrict__ gate) {
    int i = blockIdx.x * blockDim.x + threadIdx.x;
    if (i >= SS * EE) return;
    float m0 = gate[i];
    float m1 = gate[SS * EE + i];
    float den = m0 + m1 + 1e-6f;
    gate[i]           = m0 / den * 2.0f;
    gate[SS * EE + i] = m1 / den * 2.0f;
}

// ---------------------------------------------------------------------------
// K3: per (e,b): select top-CAP tokens (JAX tie-break), ascending ids.
// Also writes inverse map inv_slot[token][e] = slot (pre-memset to -1).
// ---------------------------------------------------------------------------
__global__ __launch_bounds__(1024) void select_kernel(const float* __restrict__ gate,
        int* __restrict__ seq_ids, int* __restrict__ inv_slot) {
    __shared__ float vals[SS];
    __shared__ int wsum[16];
    int eb = blockIdx.x;
    int e = eb >> 1, b = eb & 1;
    int t = threadIdx.x;
    for (int s = t; s < SS; s += 1024)
        vals[s] = gate[((size_t)b * SS + s) * EE + e];
    __syncthreads();
    int i0 = t * 2;
    float v0 = vals[i0], v1 = vals[i0 + 1];
    int r0 = 0, r1 = 0;
    for (int j = 0; j < SS; ++j) {
        float vj = vals[j];
        r0 += (int)((vj > v0) | ((vj == v0) & (j < i0)));
        r1 += (int)((vj > v1) | ((vj == v1) & (j < i0 + 1)));
    }
    int s0 = (r0 < CAPP), s1 = (r1 < CAPP);
    int cnt = s0 + s1;
    int lane = t & 63, wid = t >> 6;
    int incl = cnt;
#pragma unroll
    for (int off = 1; off < 64; off <<= 1) {
        int n = __shfl_up(incl, off, 64);
        if (lane >= off) incl += n;
    }
    if (lane == 63) wsum[wid] = incl;
    __syncthreads();
    int base = 0;
    for (int w = 0; w < wid; ++w) base += wsum[w];
    int pos = base + incl - cnt;
    if (s0) {
        seq_ids[(size_t)eb * CAPP + pos] = i0;
        inv_slot[((size_t)b * SS + i0) * EE + e] = pos;
        ++pos;
    }
    if (s1) {
        seq_ids[(size_t)eb * CAPP + pos] = i0 + 1;
        inv_slot[((size_t)b * SS + i0 + 1) * EE + e] = pos;
    }
}

// ---------------------------------------------------------------------------
// K4: q/k/v projection (gathered rows) with RoPE fused into the epilogue for
// q (nb==0) and k (nb==1). grid (20, 3, 32), block 256.
// ---------------------------------------------------------------------------
__global__ __launch_bounds__(256) void proj_kernel(const float* __restrict__ x,
        const float* __restrict__ Wq, const float* __restrict__ Wkv,
        const int* __restrict__ seq_ids, float* __restrict__ qo,
        float* __restrict__ ko, float* __restrict__ vo) {
    __shared__ float As[16][68];
    __shared__ float Bs[16][68];
    __shared__ int sids[64];
    int eb = blockIdx.z;
    int e = eb >> 1, b = eb & 1;
    int m0 = blockIdx.x * 64;
    int nb = blockIdx.y;
    int t = threadIdx.x;
    if (t < 64) sids[t] = seq_ids[(size_t)eb * CAPP + m0 + t];
    int ty = t >> 4, tx = t & 15;
    int am = t >> 2, akq = t & 3;
    const float* wsrc = (nb == 0) ? (Wq + (size_t)e * DD * HDD)
                                  : (Wkv + (size_t)e * DD * 2 * HDD + (size_t)(nb - 1) * HDD);
    int ldw = (nb == 0) ? HDD : 2 * HDD;
    float acc[4][4] = {};
    __syncthreads();
    for (int k0 = 0; k0 < DD; k0 += 16) {
        float4 av = *(const float4*)(x + ((size_t)(b * SS + sids[am])) * DD + k0 + akq * 4);
        float4 bv = *(const float4*)(wsrc + (size_t)(k0 + ty) * ldw + tx * 4);
        As[akq * 4 + 0][am] = av.x; As[akq * 4 + 1][am] = av.y;
        As[akq * 4 + 2][am] = av.z; As[akq * 4 + 3][am] = av.w;
        *(float4*)&Bs[ty][tx * 4] = bv;
        __syncthreads();
#pragma unroll
        for (int kk = 0; kk < 16; ++kk) {
            float4 a4 = *(const float4*)&As[kk][ty * 4];
            float4 b4 = *(const float4*)&Bs[kk][tx * 4];
            float a[4] = {a4.x, a4.y, a4.z, a4.w};
            float bbv[4] = {b4.x, b4.y, b4.z, b4.w};
#pragma unroll
            for (int i = 0; i < 4; ++i)
#pragma unroll
                for (int j = 0; j < 4; ++j)
                    acc[i][j] = fmaf(a[i], bbv[j], acc[i][j]);
        }
        __syncthreads();
    }
    float* dst = (nb == 0) ? qo : ((nb == 1) ? ko : vo);
    if (nb == 2) {
#pragma unroll
        for (int i = 0; i < 4; ++i) {
            float4 o = make_float4(acc[i][0], acc[i][1], acc[i][2], acc[i][3]);
            *(float4*)(dst + ((size_t)eb * CAPP + m0 + ty * 4 + i) * HDD + tx * 4) = o;
        }
    } else {
        // RoPE: col = tx*4+jj, partner col = col^32 lives at lane tx^8 (same jj)
        float sgn = (tx < 8) ? -1.0f : 1.0f;
#pragma unroll
        for (int i = 0; i < 4; ++i) {
            float p = (float)sids[ty * 4 + i];
            float o[4];
#pragma unroll
            for (int jj = 0; jj < 4; ++jj) {
                float prt = __shfl_xor(acc[i][jj], 8, 64);
                int j = (tx & 7) * 4 + jj;                 // col & 31
                float ang = p * exp2f((float)j * -0.41524101186092029f);
                float s, c;
                sincosf(ang, &s, &c);
                o[jj] = acc[i][jj] * c + sgn * prt * s;
            }
            *(float4*)(dst + ((size_t)eb * CAPP + m0 + ty * 4 + i) * HDD + tx * 4) =
                make_float4(o[0], o[1], o[2], o[3]);
        }
    }
}

// ---------------------------------------------------------------------------
// K6: causal flash attention, bf16 MFMA (16x16x32), fp32 accumulate.
// grid (32 eb, 20 qtile-reversed), block 256 = 4 waves; each wave owns a
// 16-row Q strip (A-frags in registers). K bf16 in LDS [64][72] (pad ->
// 2-way max bank aliasing, free). V transposed bf16 Vt[64][72]. P goes
// C-layout -> per-wave LDS -> A-layout. Softmax fp32, online m/l.
// ---------------------------------------------------------------------------
__global__ __launch_bounds__(256) void attn_kernel(const float* __restrict__ qi,
        const float* __restrict__ ki, const float* __restrict__ vi,
        float* __restrict__ ctx) {
    __shared__ __align__(16) unsigned short Ks[64][72];
    __shared__ __align__(16) unsigned short Vt[64][72];
    __shared__ __align__(16) unsigned short Pl[4][16][72];
    int eb = blockIdx.x;
    int qt = 19 - blockIdx.y;                     // biggest tiles dispatch first
    int qrow0 = qt * 64;
    int t = threadIdx.x;
    int w = t >> 6, l = t & 63;
    int lq = l >> 4, lr = l & 15;
    const float* qb = qi + (size_t)eb * CAPP * HDD;
    const float* kb = ki + (size_t)eb * CAPP * HDD;
    const float* vb = vi + (size_t)eb * CAPP * HDD;

    // Q strip A-frags: A[row=lr][k=lq*8+j], rows = qrow0 + w*16 + lr
    bf16x8 aq[2];
#pragma unroll
    for (int fr = 0; fr < 2; ++fr) {
        const float* qrow = qb + (size_t)(qrow0 + w * 16 + lr) * HDD + fr * 32 + lq * 8;
        float4 a0 = *(const float4*)qrow;
        float4 a1 = *(const float4*)(qrow + 4);
        aq[fr][0] = (short)f2b(a0.x); aq[fr][1] = (short)f2b(a0.y);
        aq[fr][2] = (short)f2b(a0.z); aq[fr][3] = (short)f2b(a0.w);
        aq[fr][4] = (short)f2b(a1.x); aq[fr][5] = (short)f2b(a1.y);
        aq[fr][6] = (short)f2b(a1.z); aq[fr][7] = (short)f2b(a1.w);
    }

    f32x4 O[4];
    float m_run[4], l_run[4];
#pragma unroll
    for (int cb = 0; cb < 4; ++cb) O[cb] = (f32x4){0.f, 0.f, 0.f, 0.f};
#pragma unroll
    for (int r = 0; r < 4; ++r) { m_run[r] = -INFINITY; l_run[r] = 0.0f; }

    int srow = t >> 2, scol = (t & 3) * 16;
    for (int kt = 0; kt <= qt; ++kt) {
        int krow0 = kt * 64;
        __syncthreads();
        // stage K (row-major bf16) and V (transposed bf16)
        const float* kg = kb + (size_t)(krow0 + srow) * HDD;
        const float* vg = vb + (size_t)(krow0 + srow) * HDD;
#pragma unroll
        for (int u = 0; u < 4; ++u) {
            int c = scol + u * 4;
            float4 k4 = *(const float4*)(kg + c);
            float4 v4 = *(const float4*)(vg + c);
            *(ushort4*)&Ks[srow][c] =
                make_ushort4(f2b(k4.x), f2b(k4.y), f2b(k4.z), f2b(k4.w));
            Vt[c + 0][srow] = f2b(v4.x);
            Vt[c + 1][srow] = f2b(v4.y);
            Vt[c + 2][srow] = f2b(v4.z);
            Vt[c + 3][srow] = f2b(v4.w);
        }
        __syncthreads();

        // S = Q K^T  (each wave: 16 x 64 strip)
        f32x4 S[4];
#pragma unroll
        for (int cb = 0; cb < 4; ++cb) {
            bf16x8 bk0 = *(const bf16x8*)&Ks[cb * 16 + lr][lq * 8];
            bf16x8 bk1 = *(const bf16x8*)&Ks[cb * 16 + lr][32 + lq * 8];
            f32x4 z = (f32x4){0.f, 0.f, 0.f, 0.f};
            z = __builtin_amdgcn_mfma_f32_16x16x32_bf16(aq[0], bk0, z, 0, 0, 0);
            S[cb] = __builtin_amdgcn_mfma_f32_16x16x32_bf16(aq[1], bk1, z, 0, 0, 0);
        }
        // scale + causal mask (diagonal tile only)
        if (kt == qt) {
#pragma unroll
            for (int cb = 0; cb < 4; ++cb)
#pragma unroll
                for (int r = 0; r < 4; ++r) {
                    float val = S[cb][r] * 0.125f;
                    if (cb * 16 + lr > w * 16 + lq * 4 + r) val = -INFINITY;
                    S[cb][r] = val;
                }
        } else {
#pragma unroll
            for (int cb = 0; cb < 4; ++cb)
#pragma unroll
                for (int r = 0; r < 4; ++r) S[cb][r] *= 0.125f;
        }
        // online softmax; rows live at (lq*4 + r), col group = lr (+16cb)
        float p[4][4];
#pragma unroll
        for (int r = 0; r < 4; ++r) {
            float tm = fmaxf(fmaxf(S[0][r], S[1][r]), fmaxf(S[2][r], S[3][r]));
#pragma unroll
            for (int off = 1; off < 16; off <<= 1) tm = fmaxf(tm, __shfl_xor(tm, off, 64));
            float mnew = fmaxf(m_run[r], tm);
            float fac = expf(m_run[r] - mnew);
            m_run[r] = mnew;
            float rs = 0.0f;
#pragma unroll
            for (int cb = 0; cb < 4; ++cb) {
                p[cb][r] = expf(S[cb][r] - mnew);
                rs += p[cb][r];
            }
#pragma unroll
            for (int off = 1; off < 16; off <<= 1) rs += __shfl_xor(rs, off, 64);
            l_run[r] = l_run[r] * fac + rs;
            O[0][r] *= fac; O[1][r] *= fac; O[2][r] *= fac; O[3][r] *= fac;
        }
        // P: C-layout -> per-wave LDS (rows lq*4+r, col lr+16cb)
#pragma unroll
        for (int cb = 0; cb < 4; ++cb)
#pragma unroll
            for (int r = 0; r < 4; ++r)
                Pl[w][lq * 4 + r][cb * 16 + lr] = f2b(p[cb][r]);
        // PV: A-frags from Pl (row=lr, k=lq*8+j), B-frags from Vt
        bf16x8 ap0 = *(const bf16x8*)&Pl[w][lr][lq * 8];
        bf16x8 ap1 = *(const bf16x8*)&Pl[w][lr][32 + lq * 8];
#pragma unroll
        for (int cb = 0; cb < 4; ++cb) {
            bf16x8 bv0 = *(const bf16x8*)&Vt[cb * 16 + lr][lq * 8];
            bf16x8 bv1 = *(const bf16x8*)&Vt[cb * 16 + lr][32 + lq * 8];
            O[cb] = __builtin_amdgcn_mfma_f32_16x16x32_bf16(ap0, bv0, O[cb], 0, 0, 0);
            O[cb] = __builtin_amdgcn_mfma_f32_16x16x32_bf16(ap1, bv1, O[cb], 0, 0, 0);
        }
    }
    float invl[4];
#pragma unroll
    for (int r = 0; r < 4; ++r) invl[r] = 1.0f / l_run[r];
    float* cbase = ctx + ((size_t)eb * CAPP + qrow0 + w * 16 + lq * 4) * HDD;
#pragma unroll
    for (int r = 0; r < 4; ++r)
#pragma unroll
        for (int cb = 0; cb < 4; ++cb)
            cbase[(size_t)r * HDD + cb * 16 + lr] = O[cb][r] * invl[r];
}

// ---------------------------------------------------------------------------
// K7: token-major combine — NO atomics. grid (B*S/64, D/128), block 256.
// combined[token][d] = sum_e w_e*(ctx[e,b,slot]·Wff[e][:,d]) + (sum_e w_e)*bff[d]
// ---------------------------------------------------------------------------
__global__ __launch_bounds__(256) void combine_kernel(const float* __restrict__ ctx,
        const float* __restrict__ Wff, const float* __restrict__ bff,
        const int* __restrict__ inv_slot, const float* __restrict__ gate,
        float* __restrict__ combined) {
    __shared__ float AsT[64][68];      // [k][token-row], weighted
    __shared__ float Bs[64][132];      // [k][n]
    __shared__ int slotL[64];
    __shared__ float wL[64];
    int tb = blockIdx.x * 64;          // flat token base (same b within tile)
    int b = tb / SS;
    int n0 = blockIdx.y * 128;
    int t = threadIdx.x;
    int ty = t >> 5, tx = t & 31;      // 8 x 32 -> each thread 8 rows x 4 cols
    float acc[8][4] = {};
    float wsum[8] = {};
    for (int e = 0; e < EE; ++e) {
        __syncthreads();
        if (t < 64) {
            int slot = inv_slot[(size_t)(tb + t) * EE + e];
            slotL[t] = slot;
            wL[t] = (slot >= 0) ? gate[(size_t)(tb + t) * EE + e] : 0.0f;
        }
        __syncthreads();
        const float* cb = ctx + ((size_t)(e * BB + b)) * CAPP * HDD;
#pragma unroll
        for (int i = 0; i < 4; ++i) {
            int idx = t + i * 256;              // 0..1023
            int r = idx >> 4, c4 = (idx & 15) * 4;
            int slot = slotL[r];
            float w = wL[r];
            float4 v = make_float4(0.f, 0.f, 0.f, 0.f);
            if (slot >= 0 && w != 0.0f)
                v = *(const float4*)(cb + (size_t)slot * HDD + c4);
            AsT[c4 + 0][r] = v.x * w; AsT[c4 + 1][r] = v.y * w;
            AsT[c4 + 2][r] = v.z * w; AsT[c4 + 3][r] = v.w * w;
        }
        const float* wb = Wff + (size_t)e * HDD * DD + n0;
#pragma unroll
        for (int i = 0; i < 8; ++i) {
            int idx = t + i * 256;              // 0..2047
            int r = idx >> 5, c4 = (idx & 31) * 4;
            *(float4*)&Bs[r][c4] = *(const float4*)(wb + (size_t)r * DD + c4);
        }
        __syncthreads();
#pragma unroll 8
        for (int kk = 0; kk < 64; ++kk) {
            float4 b4 = *(const float4*)&Bs[kk][tx * 4];
            float4 a0 = *(const float4*)&AsT[kk][ty * 8];
            float4 a1 = *(const float4*)&AsT[kk][ty * 8 + 4];
            float a[8] = {a0.x, a0.y, a0.z, a0.w, a1.x, a1.y, a1.z, a1.w};
#pragma unroll
            for (int i = 0; i < 8; ++i) {
                acc[i][0] = fmaf(a[i], b4.x, acc[i][0]);
                acc[i][1] = fmaf(a[i], b4.y, acc[i][1]);
                acc[i][2] = fmaf(a[i], b4.z, acc[i][2]);
                acc[i][3] = fmaf(a[i], b4.w, acc[i][3]);
            }
        }
#pragma unroll
        for (int i = 0; i < 8; ++i) wsum[i] += wL[ty * 8 + i];
    }
    float4 bf = *(const float4*)(bff + n0 + tx * 4);
#pragma unroll
    for (int i = 0; i < 8; ++i) {
        int token = tb + ty * 8 + i;
        float4 o = make_float4(acc[i][0] + wsum[i] * bf.x,
                               acc[i][1] + wsum[i] * bf.y,
                               acc[i][2] + wsum[i] * bf.z,
                               acc[i][3] + wsum[i] * bf.w);
        *(float4*)(combined + (size_t)token * DD + n0 + tx * 4) = o;
    }
}

// ---------------------------------------------------------------------------
// K8: h = x + combined ; LayerNorm(D) -> out
// ---------------------------------------------------------------------------
__global__ __launch_bounds__(256) void ln_kernel(const float* __restrict__ x,
        const float* __restrict__ combined, const float* __restrict__ gamma,
        const float* __restrict__ beta, float* __restrict__ out) {
    __shared__ float rsum[4], rsq[4];
    int token = blockIdx.x;
    int t = threadIdx.x;
    const float4* xr = (const float4*)(x + (size_t)token * DD);
    const float4* cr = (const float4*)(combined + (size_t)token * DD);
    float4 xv = xr[t], cv = cr[t];
    float4 h = make_float4(xv.x + cv.x, xv.y + cv.y, xv.z + cv.z, xv.w + cv.w);
    float sum = h.x + h.y + h.z + h.w;
    float sq  = h.x * h.x + h.y * h.y + h.z * h.z + h.w * h.w;
    int lane = t & 63, wid = t >> 6;
#pragma unroll
    for (int off = 32; off > 0; off >>= 1) {
        sum += __shfl_xor(sum, off, 64);
        sq  += __shfl_xor(sq, off, 64);
    }
    if (lane == 0) { rsum[wid] = sum; rsq[wid] = sq; }
    __syncthreads();
    float ts = rsum[0] + rsum[1] + rsum[2] + rsum[3];
    float tq = rsq[0] + rsq[1] + rsq[2] + rsq[3];
    float mu = ts * (1.0f / DD);
    float var = tq * (1.0f / DD) - mu * mu;
    float inv = rsqrtf(var + 1e-5f);
    float4 g = ((const float4*)gamma)[t];
    float4 be = ((const float4*)beta)[t];
    float4 o;
    o.x = (h.x - mu) * inv * g.x + be.x;
    o.y = (h.y - mu) * inv * g.y + be.y;
    o.z = (h.z - mu) * inv * g.z + be.z;
    o.w = (h.w - mu) * inv * g.w + be.w;
    ((float4*)(out + (size_t)token * DD))[t] = o;
}

// ---------------------------------------------------------------------------
extern "C" void kernel_launch(void* const* d_in, const int* in_sizes, int n_in,
                              void* d_out, int out_size, void* d_ws, size_t ws_size,
                              hipStream_t stream) {
    const float* x        = (const float*)d_in[0];
    const float* w_gate   = (const float*)d_in[1];
    const float* b_gate   = (const float*)d_in[2];
    const float* Wq       = (const float*)d_in[3];
    const float* Wkv      = (const float*)d_in[4];
    const float* Wff      = (const float*)d_in[5];
    const float* bff      = (const float*)d_in[6];
    const float* ln_gamma = (const float*)d_in[7];
    const float* ln_beta  = (const float*)d_in[8];
    float* out = (float*)d_out;
    char* ws = (char*)d_ws;

    // workspace layout (bytes); total ~59.4 MB
    float* gate     = (float*)(ws + 0);           // B*S*E            262144
    int*   seq_ids  = (int*)  (ws + 262144);      // E*B*CAP          163840
    int*   inv_slot = (int*)  (ws + 425984);      // B*S*E            262144
    float* qbuf     = (float*)(ws + 688128);      // E*B*CAP*HD       10485760
    float* kbuf     = (float*)(ws + 11173888);
    float* vbuf     = (float*)(ws + 21659648);
    float* ctx      = (float*)(ws + 32145408);
    float* combined = (float*)(ws + 42631168);    // B*S*D            16777216

    hipMemsetAsync(inv_slot, 0xFF, (size_t)BB * SS * EE * sizeof(int), stream);

    gate_kernel<<<BB * SS / 4, 256, 0, stream>>>(x, w_gate, b_gate, gate);
    route_kernel<<<(SS * EE + 255) / 256, 256, 0, stream>>>(gate);
    select_kernel<<<EE * BB, 1024, 0, stream>>>(gate, seq_ids, inv_slot);
    proj_kernel<<<dim3(CAPP / 64, 3, EE * BB), 256, 0, stream>>>(x, Wq, Wkv, seq_ids,
                                                                 qbuf, kbuf, vbuf);
    attn_kernel<<<dim3(EE * BB, CAPP / 64), 256, 0, stream>>>(qbuf, kbuf, vbuf, ctx);
    combine_kernel<<<dim3(BB * SS / 64, DD / 128), 256, 0, stream>>>(
        ctx, Wff, bff, inv_slot, gate, combined);
    ln_kernel<<<BB * SS, 256, 0, stream>>>(x, combined, ln_gamma, ln_beta, out);
}

// Round 6
// 591.360 us; speedup vs baseline: 2.9579x; 1.1627x over previous
//
#include <hip/hip_runtime.h>
#include <math.h>

#define BB 2
#define SS 2048
#define DD 1024
#define EE 16
#define HDD 64
#define CAPP 1280
#define TOPKK 8

typedef __attribute__((ext_vector_type(8))) short bf16x8;
typedef __attribute__((ext_vector_type(4))) float f32x4;

static __device__ __forceinline__ unsigned short f2b(float f) {
    union { float f; unsigned u; } v; v.f = f;
    unsigned r = v.u + 0x7FFF + ((v.u >> 16) & 1);   // RNE
    return (unsigned short)(r >> 16);
}

// ---------------------------------------------------------------------------
// P0: x -> bf16
// ---------------------------------------------------------------------------
__global__ __launch_bounds__(256) void xcvt_kernel(const float* __restrict__ x,
        short* __restrict__ xb) {
    size_t base = ((size_t)blockIdx.x * 256 + threadIdx.x) * 8;
    float4 a = *(const float4*)(x + base);
    float4 b = *(const float4*)(x + base + 4);
    bf16x8 o;
    o[0] = (short)f2b(a.x); o[1] = (short)f2b(a.y);
    o[2] = (short)f2b(a.z); o[3] = (short)f2b(a.w);
    o[4] = (short)f2b(b.x); o[5] = (short)f2b(b.y);
    o[6] = (short)f2b(b.z); o[7] = (short)f2b(b.w);
    *(bf16x8*)(xb + base) = o;
}

// ---------------------------------------------------------------------------
// P1: pack + transpose weights to WallT[e][col 0..191][k 0..1023] bf16
// cols 0-63 = Wq, 64-127 = Wkv[:, :64] (k), 128-191 = Wkv[:, 64:] (v)
// grid (6, 32, E): 32x32 tile transpose via LDS
// ---------------------------------------------------------------------------
__global__ __launch_bounds__(256) void wcvt_kernel(const float* __restrict__ Wq,
        const float* __restrict__ Wkv, short* __restrict__ WallT) {
    __shared__ float tile[32][33];
    int e = blockIdx.z;
    int c0 = blockIdx.x * 32;
    int d0 = blockIdx.y * 32;
    int t = threadIdx.x;
#pragma unroll
    for (int i = 0; i < 4; ++i) {
        int idx = t + i * 256;
        int d = idx >> 5, c = idx & 31;
        float v;
        if (c0 < 64)
            v = Wq[((size_t)e * DD + d0 + d) * HDD + c0 + c];
        else
            v = Wkv[((size_t)e * DD + d0 + d) * 2 * HDD + (c0 - 64 + c)];
        tile[d][c] = v;
    }
    __syncthreads();
#pragma unroll
    for (int i = 0; i < 4; ++i) {
        int idx = t + i * 256;
        int cr = idx >> 5, d2 = idx & 31;
        WallT[((size_t)e * 192 + c0 + cr) * DD + d0 + d2] = (short)f2b(tile[d2][cr]);
    }
}

// ---------------------------------------------------------------------------
// K1: gating — logits = x @ w_gate + b_gate, softmax over E, top-8 mask, mg
// ---------------------------------------------------------------------------
__global__ __launch_bounds__(256) void gate_kernel(const float* __restrict__ x,
        const float* __restrict__ wg, const float* __restrict__ bg,
        float* __restrict__ gate) {
    int token = blockIdx.x * 4 + (threadIdx.x >> 6);
    int lane = threadIdx.x & 63;
    const float* xr = x + (size_t)token * DD;
    float acc[EE];
#pragma unroll
    for (int e = 0; e < EE; ++e) acc[e] = 0.0f;
    for (int d = lane; d < DD; d += 64) {
        float xv = xr[d];
        const float4* wr = (const float4*)(wg + (size_t)d * EE);
        float4 w0 = wr[0], w1 = wr[1], w2 = wr[2], w3 = wr[3];
        acc[0]  = fmaf(xv, w0.x, acc[0]);  acc[1]  = fmaf(xv, w0.y, acc[1]);
        acc[2]  = fmaf(xv, w0.z, acc[2]);  acc[3]  = fmaf(xv, w0.w, acc[3]);
        acc[4]  = fmaf(xv, w1.x, acc[4]);  acc[5]  = fmaf(xv, w1.y, acc[5]);
        acc[6]  = fmaf(xv, w1.z, acc[6]);  acc[7]  = fmaf(xv, w1.w, acc[7]);
        acc[8]  = fmaf(xv, w2.x, acc[8]);  acc[9]  = fmaf(xv, w2.y, acc[9]);
        acc[10] = fmaf(xv, w2.z, acc[10]); acc[11] = fmaf(xv, w2.w, acc[11]);
        acc[12] = fmaf(xv, w3.x, acc[12]); acc[13] = fmaf(xv, w3.y, acc[13]);
        acc[14] = fmaf(xv, w3.z, acc[14]); acc[15] = fmaf(xv, w3.w, acc[15]);
    }
#pragma unroll
    for (int e = 0; e < EE; ++e) {
        float v = acc[e];
#pragma unroll
        for (int off = 32; off > 0; off >>= 1) v += __shfl_xor(v, off, 64);
        acc[e] = v + bg[e];
    }
    float mx = acc[0];
#pragma unroll
    for (int e = 1; e < EE; ++e) mx = fmaxf(mx, acc[e]);
    float sum = 0.0f;
#pragma unroll
    for (int e = 0; e < EE; ++e) { acc[e] = expf(acc[e] - mx); sum += acc[e]; }
    float inv = 1.0f / sum;
#pragma unroll
    for (int e = 0; e < EE; ++e) acc[e] *= inv;
    if (lane == 0) {
#pragma unroll
        for (int e = 0; e < EE; ++e) {
            int rank = 0;
#pragma unroll
            for (int j = 0; j < EE; ++j)
                rank += (acc[j] > acc[e]) || (acc[j] == acc[e] && j < e);
            gate[(size_t)token * EE + e] = (rank < TOPKK) ? acc[e] : 0.0f;
        }
    }
}

// ---------------------------------------------------------------------------
// K2: route = mg / (mg.sum over batch + eps) * capacity   (in place)
// ---------------------------------------------------------------------------
__global__ void route_kernel(float* __restrict__ gate) {
    int i = blockIdx.x * blockDim.x + threadIdx.x;
    if (i >= SS * EE) return;
    float m0 = gate[i];
    float m1 = gate[SS * EE + i];
    float den = m0 + m1 + 1e-6f;
    gate[i]           = m0 / den * 2.0f;
    gate[SS * EE + i] = m1 / den * 2.0f;
}

// ---------------------------------------------------------------------------
// K3: per (e,b): select top-CAP tokens (JAX tie-break), ascending ids.
// Also writes inverse map inv_slot[token][e] = slot (pre-memset to -1).
// ---------------------------------------------------------------------------
__global__ __launch_bounds__(1024) void select_kernel(const float* __restrict__ gate,
        int* __restrict__ seq_ids, int* __restrict__ inv_slot) {
    __shared__ float vals[SS];
    __shared__ int wsum[16];
    int eb = blockIdx.x;
    int e = eb >> 1, b = eb & 1;
    int t = threadIdx.x;
    for (int s = t; s < SS; s += 1024)
        vals[s] = gate[((size_t)b * SS + s) * EE + e];
    __syncthreads();
    int i0 = t * 2;
    float v0 = vals[i0], v1 = vals[i0 + 1];
    int r0 = 0, r1 = 0;
    for (int j = 0; j < SS; ++j) {
        float vj = vals[j];
        r0 += (int)((vj > v0) | ((vj == v0) & (j < i0)));
        r1 += (int)((vj > v1) | ((vj == v1) & (j < i0 + 1)));
    }
    int s0 = (r0 < CAPP), s1 = (r1 < CAPP);
    int cnt = s0 + s1;
    int lane = t & 63, wid = t >> 6;
    int incl = cnt;
#pragma unroll
    for (int off = 1; off < 64; off <<= 1) {
        int n = __shfl_up(incl, off, 64);
        if (lane >= off) incl += n;
    }
    if (lane == 63) wsum[wid] = incl;
    __syncthreads();
    int base = 0;
    for (int w = 0; w < wid; ++w) base += wsum[w];
    int pos = base + incl - cnt;
    if (s0) {
        seq_ids[(size_t)eb * CAPP + pos] = i0;
        inv_slot[((size_t)b * SS + i0) * EE + e] = pos;
        ++pos;
    }
    if (s1) {
        seq_ids[(size_t)eb * CAPP + pos] = i0 + 1;
        inv_slot[((size_t)b * SS + i0 + 1) * EE + e] = pos;
    }
}

// ---------------------------------------------------------------------------
// K4: q/k/v projection — bf16 MFMA, LDS-free, RoPE fused, q|k|v in one pass.
// grid (20 m-tiles, 32 eb), block 256 = 4 waves; wave owns 16 slots x 192 cols.
// A-frags from gathered xb rows, B-frags from WallT (both 16B/lane).
// ---------------------------------------------------------------------------
__global__ __launch_bounds__(256) void proj_kernel(const short* __restrict__ xb,
        const short* __restrict__ WallT, const int* __restrict__ seq_ids,
        short* __restrict__ qo, short* __restrict__ ko, short* __restrict__ vo) {
    __shared__ int sids[64];
    int eb = blockIdx.y;
    int e = eb >> 1, b = eb & 1;
    int m0 = blockIdx.x * 64;
    int t = threadIdx.x;
    int w = t >> 6, l = t & 63, lq = l >> 4, lr = l & 15;
    if (t < 64) sids[t] = seq_ids[(size_t)eb * CAPP + m0 + t];
    __syncthreads();
    const short* xrow = xb + (size_t)(b * SS + sids[w * 16 + lr]) * DD + lq * 8;
    const short* wTl = WallT + (size_t)e * 192 * DD + (size_t)lr * DD + lq * 8;
    f32x4 acc[12];
#pragma unroll
    for (int cb = 0; cb < 12; ++cb) acc[cb] = (f32x4){0.f, 0.f, 0.f, 0.f};
#pragma unroll 2
    for (int k0 = 0; k0 < DD; k0 += 32) {
        bf16x8 a = *(const bf16x8*)(xrow + k0);
#pragma unroll
        for (int cb = 0; cb < 12; ++cb) {
            bf16x8 bw = *(const bf16x8*)(wTl + (size_t)cb * 16 * DD + k0);
            acc[cb] = __builtin_amdgcn_mfma_f32_16x16x32_bf16(a, bw, acc[cb], 0, 0, 0);
        }
    }
    // epilogue: RoPE on q (cb 0-3) and k (cb 4-7); v (cb 8-11) plain.
    // col = cb*16+lr; pairs (c, c+32) = (cb, cb+2) same lane; j = (cb&1)*16+lr
    float f0 = exp2f(-(float)lr * 0.41524101186092029f);
    float f1 = exp2f(-(float)(16 + lr) * 0.41524101186092029f);
#pragma unroll
    for (int r = 0; r < 4; ++r) {
        int rrow = w * 16 + lq * 4 + r;
        float p = (float)sids[rrow];
        float s0, c0, s1, c1;
        sincosf(p * f0, &s0, &c0);
        sincosf(p * f1, &s1, &c1);
        size_t obase = ((size_t)eb * CAPP + m0 + rrow) * HDD;
        float q0 = acc[0][r] * c0 - acc[2][r] * s0;
        float q2 = acc[2][r] * c0 + acc[0][r] * s0;
        float q1 = acc[1][r] * c1 - acc[3][r] * s1;
        float q3 = acc[3][r] * c1 + acc[1][r] * s1;
        qo[obase + lr]      = (short)f2b(q0);
        qo[obase + 16 + lr] = (short)f2b(q1);
        qo[obase + 32 + lr] = (short)f2b(q2);
        qo[obase + 48 + lr] = (short)f2b(q3);
        float k0v = acc[4][r] * c0 - acc[6][r] * s0;
        float k2v = acc[6][r] * c0 + acc[4][r] * s0;
        float k1v = acc[5][r] * c1 - acc[7][r] * s1;
        float k3v = acc[7][r] * c1 + acc[5][r] * s1;
        ko[obase + lr]      = (short)f2b(k0v);
        ko[obase + 16 + lr] = (short)f2b(k1v);
        ko[obase + 32 + lr] = (short)f2b(k2v);
        ko[obase + 48 + lr] = (short)f2b(k3v);
#pragma unroll
        for (int u = 0; u < 4; ++u)
            vo[obase + u * 16 + lr] = (short)f2b(acc[8 + u][r]);
    }
}

// ---------------------------------------------------------------------------
// K6: causal flash attention, bf16 in / bf16 MFMA / fp32 out.
// grid (32 eb, 20 qtile-reversed), block 256 = 4 waves.
// ---------------------------------------------------------------------------
__global__ __launch_bounds__(256) void attn_kernel(const short* __restrict__ qi,
        const short* __restrict__ ki, const short* __restrict__ vi,
        float* __restrict__ ctx) {
    __shared__ __align__(16) short Ks[64][72];
    __shared__ __align__(16) short Vt[64][72];
    __shared__ __align__(16) short Pl[4][16][72];
    int eb = blockIdx.x;
    int qt = 19 - blockIdx.y;                     // biggest tiles dispatch first
    int qrow0 = qt * 64;
    int t = threadIdx.x;
    int w = t >> 6, l = t & 63;
    int lq = l >> 4, lr = l & 15;
    const short* qb = qi + (size_t)eb * CAPP * HDD;
    const short* kb = ki + (size_t)eb * CAPP * HDD;
    const short* vb = vi + (size_t)eb * CAPP * HDD;

    // Q strip A-frags: A[row=lr][k=lq*8+j], rows = qrow0 + w*16 + lr
    const short* qrow = qb + (size_t)(qrow0 + w * 16 + lr) * HDD + lq * 8;
    bf16x8 aq[2];
    aq[0] = *(const bf16x8*)qrow;
    aq[1] = *(const bf16x8*)(qrow + 32);

    f32x4 O[4];
    float m_run[4], l_run[4];
#pragma unroll
    for (int cb = 0; cb < 4; ++cb) O[cb] = (f32x4){0.f, 0.f, 0.f, 0.f};
#pragma unroll
    for (int r = 0; r < 4; ++r) { m_run[r] = -INFINITY; l_run[r] = 0.0f; }

    int srow = t >> 2, scol = (t & 3) * 16;
    for (int kt = 0; kt <= qt; ++kt) {
        int krow0 = kt * 64;
        __syncthreads();
        const short* kg = kb + (size_t)(krow0 + srow) * HDD + scol;
        const short* vg = vb + (size_t)(krow0 + srow) * HDD + scol;
        bf16x8 kv0 = *(const bf16x8*)kg;
        bf16x8 kv1 = *(const bf16x8*)(kg + 8);
        bf16x8 vv0 = *(const bf16x8*)vg;
        bf16x8 vv1 = *(const bf16x8*)(vg + 8);
        *(bf16x8*)&Ks[srow][scol] = kv0;
        *(bf16x8*)&Ks[srow][scol + 8] = kv1;
#pragma unroll
        for (int u = 0; u < 8; ++u) {
            Vt[scol + u][srow] = vv0[u];
            Vt[scol + 8 + u][srow] = vv1[u];
        }
        __syncthreads();

        // S = Q K^T  (each wave: 16 x 64 strip)
        f32x4 S[4];
#pragma unroll
        for (int cb = 0; cb < 4; ++cb) {
            bf16x8 bk0 = *(const bf16x8*)&Ks[cb * 16 + lr][lq * 8];
            bf16x8 bk1 = *(const bf16x8*)&Ks[cb * 16 + lr][32 + lq * 8];
            f32x4 z = (f32x4){0.f, 0.f, 0.f, 0.f};
            z = __builtin_amdgcn_mfma_f32_16x16x32_bf16(aq[0], bk0, z, 0, 0, 0);
            S[cb] = __builtin_amdgcn_mfma_f32_16x16x32_bf16(aq[1], bk1, z, 0, 0, 0);
        }
        if (kt == qt) {
#pragma unroll
            for (int cb = 0; cb < 4; ++cb)
#pragma unroll
                for (int r = 0; r < 4; ++r) {
                    float val = S[cb][r] * 0.125f;
                    if (cb * 16 + lr > w * 16 + lq * 4 + r) val = -INFINITY;
                    S[cb][r] = val;
                }
        } else {
#pragma unroll
            for (int cb = 0; cb < 4; ++cb)
#pragma unroll
                for (int r = 0; r < 4; ++r) S[cb][r] *= 0.125f;
        }
        float p[4][4];
#pragma unroll
        for (int r = 0; r < 4; ++r) {
            float tm = fmaxf(fmaxf(S[0][r], S[1][r]), fmaxf(S[2][r], S[3][r]));
#pragma unroll
            for (int off = 1; off < 16; off <<= 1) tm = fmaxf(tm, __shfl_xor(tm, off, 64));
            float mnew = fmaxf(m_run[r], tm);
            float fac = expf(m_run[r] - mnew);
            m_run[r] = mnew;
            float rs = 0.0f;
#pragma unroll
            for (int cb = 0; cb < 4; ++cb) {
                p[cb][r] = expf(S[cb][r] - mnew);
                rs += p[cb][r];
            }
#pragma unroll
            for (int off = 1; off < 16; off <<= 1) rs += __shfl_xor(rs, off, 64);
            l_run[r] = l_run[r] * fac + rs;
            O[0][r] *= fac; O[1][r] *= fac; O[2][r] *= fac; O[3][r] *= fac;
        }
#pragma unroll
        for (int cb = 0; cb < 4; ++cb)
#pragma unroll
            for (int r = 0; r < 4; ++r)
                Pl[w][lq * 4 + r][cb * 16 + lr] = (short)f2b(p[cb][r]);
        bf16x8 ap0 = *(const bf16x8*)&Pl[w][lr][lq * 8];
        bf16x8 ap1 = *(const bf16x8*)&Pl[w][lr][32 + lq * 8];
#pragma unroll
        for (int cb = 0; cb < 4; ++cb) {
            bf16x8 bv0 = *(const bf16x8*)&Vt[cb * 16 + lr][lq * 8];
            bf16x8 bv1 = *(const bf16x8*)&Vt[cb * 16 + lr][32 + lq * 8];
            O[cb] = __builtin_amdgcn_mfma_f32_16x16x32_bf16(ap0, bv0, O[cb], 0, 0, 0);
            O[cb] = __builtin_amdgcn_mfma_f32_16x16x32_bf16(ap1, bv1, O[cb], 0, 0, 0);
        }
    }
    float invl[4];
#pragma unroll
    for (int r = 0; r < 4; ++r) invl[r] = 1.0f / l_run[r];
    float* cbase = ctx + ((size_t)eb * CAPP + qrow0 + w * 16 + lq * 4) * HDD;
#pragma unroll
    for (int r = 0; r < 4; ++r)
#pragma unroll
        for (int cb = 0; cb < 4; ++cb)
            cbase[(size_t)r * HDD + cb * 16 + lr] = O[cb][r] * invl[r];
}

// ---------------------------------------------------------------------------
// K7: token-major combine — NO atomics. grid (B*S/64, D/128), block 256.
// ---------------------------------------------------------------------------
__global__ __launch_bounds__(256) void combine_kernel(const float* __restrict__ ctx,
        const float* __restrict__ Wff, const float* __restrict__ bff,
        const int* __restrict__ inv_slot, const float* __restrict__ gate,
        float* __restrict__ combined) {
    __shared__ float AsT[64][68];      // [k][token-row], weighted
    __shared__ float Bs[64][132];      // [k][n]
    __shared__ int slotL[64];
    __shared__ float wL[64];
    int tb = blockIdx.x * 64;
    int b = tb / SS;
    int n0 = blockIdx.y * 128;
    int t = threadIdx.x;
    int ty = t >> 5, tx = t & 31;
    float acc[8][4] = {};
    float wsum[8] = {};
    for (int e = 0; e < EE; ++e) {
        __syncthreads();
        if (t < 64) {
            int slot = inv_slot[(size_t)(tb + t) * EE + e];
            slotL[t] = slot;
            wL[t] = (slot >= 0) ? gate[(size_t)(tb + t) * EE + e] : 0.0f;
        }
        __syncthreads();
        const float* cb = ctx + ((size_t)(e * BB + b)) * CAPP * HDD;
#pragma unroll
        for (int i = 0; i < 4; ++i) {
            int idx = t + i * 256;
            int r = idx >> 4, c4 = (idx & 15) * 4;
            int slot = slotL[r];
            float w = wL[r];
            float4 v = make_float4(0.f, 0.f, 0.f, 0.f);
            if (slot >= 0 && w != 0.0f)
                v = *(const float4*)(cb + (size_t)slot * HDD + c4);
            AsT[c4 + 0][r] = v.x * w; AsT[c4 + 1][r] = v.y * w;
            AsT[c4 + 2][r] = v.z * w; AsT[c4 + 3][r] = v.w * w;
        }
        const float* wb = Wff + (size_t)e * HDD * DD + n0;
#pragma unroll
        for (int i = 0; i < 8; ++i) {
            int idx = t + i * 256;
            int r = idx >> 5, c4 = (idx & 31) * 4;
            *(float4*)&Bs[r][c4] = *(const float4*)(wb + (size_t)r * DD + c4);
        }
        __syncthreads();
#pragma unroll 8
        for (int kk = 0; kk < 64; ++kk) {
            float4 b4 = *(const float4*)&Bs[kk][tx * 4];
            float4 a0 = *(const float4*)&AsT[kk][ty * 8];
            float4 a1 = *(const float4*)&AsT[kk][ty * 8 + 4];
            float a[8] = {a0.x, a0.y, a0.z, a0.w, a1.x, a1.y, a1.z, a1.w};
#pragma unroll
            for (int i = 0; i < 8; ++i) {
                acc[i][0] = fmaf(a[i], b4.x, acc[i][0]);
                acc[i][1] = fmaf(a[i], b4.y, acc[i][1]);
                acc[i][2] = fmaf(a[i], b4.z, acc[i][2]);
                acc[i][3] = fmaf(a[i], b4.w, acc[i][3]);
            }
        }
#pragma unroll
        for (int i = 0; i < 8; ++i) wsum[i] += wL[ty * 8 + i];
    }
    float4 bf = *(const float4*)(bff + n0 + tx * 4);
#pragma unroll
    for (int i = 0; i < 8; ++i) {
        int token = tb + ty * 8 + i;
        float4 o = make_float4(acc[i][0] + wsum[i] * bf.x,
                               acc[i][1] + wsum[i] * bf.y,
                               acc[i][2] + wsum[i] * bf.z,
                               acc[i][3] + wsum[i] * bf.w);
        *(float4*)(combined + (size_t)token * DD + n0 + tx * 4) = o;
    }
}

// ---------------------------------------------------------------------------
// K8: h = x + combined ; LayerNorm(D) -> out
// ---------------------------------------------------------------------------
__global__ __launch_bounds__(256) void ln_kernel(const float* __restrict__ x,
        const float* __restrict__ combined, const float* __restrict__ gamma,
        const float* __restrict__ beta, float* __restrict__ out) {
    __shared__ float rsum[4], rsq[4];
    int token = blockIdx.x;
    int t = threadIdx.x;
    const float4* xr = (const float4*)(x + (size_t)token * DD);
    const float4* cr = (const float4*)(combined + (size_t)token * DD);
    float4 xv = xr[t], cv = cr[t];
    float4 h = make_float4(xv.x + cv.x, xv.y + cv.y, xv.z + cv.z, xv.w + cv.w);
    float sum = h.x + h.y + h.z + h.w;
    float sq  = h.x * h.x + h.y * h.y + h.z * h.z + h.w * h.w;
    int lane = t & 63, wid = t >> 6;
#pragma unroll
    for (int off = 32; off > 0; off >>= 1) {
        sum += __shfl_xor(sum, off, 64);
        sq  += __shfl_xor(sq, off, 64);
    }
    if (lane == 0) { rsum[wid] = sum; rsq[wid] = sq; }
    __syncthreads();
    float ts = rsum[0] + rsum[1] + rsum[2] + rsum[3];
    float tq = rsq[0] + rsq[1] + rsq[2] + rsq[3];
    float mu = ts * (1.0f / DD);
    float var = tq * (1.0f / DD) - mu * mu;
    float inv = rsqrtf(var + 1e-5f);
    float4 g = ((const float4*)gamma)[t];
    float4 be = ((const float4*)beta)[t];
    float4 o;
    o.x = (h.x - mu) * inv * g.x + be.x;
    o.y = (h.y - mu) * inv * g.y + be.y;
    o.z = (h.z - mu) * inv * g.z + be.z;
    o.w = (h.w - mu) * inv * g.w + be.w;
    ((float4*)(out + (size_t)token * DD))[t] = o;
}

// ---------------------------------------------------------------------------
extern "C" void kernel_launch(void* const* d_in, const int* in_sizes, int n_in,
                              void* d_out, int out_size, void* d_ws, size_t ws_size,
                              hipStream_t stream) {
    const float* x        = (const float*)d_in[0];
    const float* w_gate   = (const float*)d_in[1];
    const float* b_gate   = (const float*)d_in[2];
    const float* Wq       = (const float*)d_in[3];
    const float* Wkv      = (const float*)d_in[4];
    const float* Wff      = (const float*)d_in[5];
    const float* bff      = (const float*)d_in[6];
    const float* ln_gamma = (const float*)d_in[7];
    const float* ln_beta  = (const float*)d_in[8];
    float* out = (float*)d_out;
    char* ws = (char*)d_ws;

    // workspace layout (bytes); total ~58.4 MB
    float* gate     = (float*)(ws + 0);           // B*S*E fp32        262144
    int*   seq_ids  = (int*)  (ws + 262144);      // E*B*CAP           163840
    int*   inv_slot = (int*)  (ws + 425984);      // B*S*E             262144
    short* xb       = (short*)(ws + 688128);      // B*S*D bf16        8388608
    short* WallT    = (short*)(ws + 9076736);     // E*192*D bf16      6291456
    short* qb       = (short*)(ws + 15368192);    // E*B*CAP*HD bf16   5242880
    short* kb       = (short*)(ws + 20611072);
    short* vb       = (short*)(ws + 25853952);
    float* ctx      = (float*)(ws + 31096832);    // E*B*CAP*HD fp32   10485760
    float* combined = (float*)(ws + 41582592);    // B*S*D fp32        16777216

    hipMemsetAsync(inv_slot, 0xFF, (size_t)BB * SS * EE * sizeof(int), stream);

    xcvt_kernel<<<BB * SS * DD / 8 / 256, 256, 0, stream>>>(x, xb);
    wcvt_kernel<<<dim3(6, 32, EE), 256, 0, stream>>>(Wq, Wkv, WallT);
    gate_kernel<<<BB * SS / 4, 256, 0, stream>>>(x, w_gate, b_gate, gate);
    route_kernel<<<(SS * EE + 255) / 256, 256, 0, stream>>>(gate);
    select_kernel<<<EE * BB, 1024, 0, stream>>>(gate, seq_ids, inv_slot);
    proj_kernel<<<dim3(CAPP / 64, EE * BB), 256, 0, stream>>>(xb, WallT, seq_ids,
                                                              qb, kb, vb);
    attn_kernel<<<dim3(EE * BB, CAPP / 64), 256, 0, stream>>>(qb, kb, vb, ctx);
    combine_kernel<<<dim3(BB * SS / 64, DD / 128), 256, 0, stream>>>(
        ctx, Wff, bff, inv_slot, gate, combined);
    ln_kernel<<<BB * SS, 256, 0, stream>>>(x, combined, ln_gamma, ln_beta, out);
}

// Round 10
// 414.698 us; speedup vs baseline: 4.2180x; 1.4260x over previous
//
#include <hip/hip_runtime.h>
#include <math.h>

#define BB 2
#define SS 2048
#define DD 1024
#define EE 16
#define HDD 64
#define CAPP 1280
#define TOPKK 8

typedef __attribute__((ext_vector_type(8))) short bf16x8;
typedef __attribute__((ext_vector_type(4))) float f32x4;

static __device__ __forceinline__ unsigned short f2b(float f) {
    union { float f; unsigned u; } v; v.f = f;
    unsigned r = v.u + 0x7FFF + ((v.u >> 16) & 1);   // RNE
    return (unsigned short)(r >> 16);
}
static __device__ __forceinline__ float b2f(short s) {
    union { unsigned u; float f; } v;
    v.u = ((unsigned)(unsigned short)s) << 16;
    return v.f;
}

// ---------------------------------------------------------------------------
// P0: x -> bf16
// ---------------------------------------------------------------------------
__global__ __launch_bounds__(256) void xcvt_kernel(const float* __restrict__ x,
        short* __restrict__ xb) {
    size_t base = ((size_t)blockIdx.x * 256 + threadIdx.x) * 8;
    float4 a = *(const float4*)(x + base);
    float4 b = *(const float4*)(x + base + 4);
    bf16x8 o;
    o[0] = (short)f2b(a.x); o[1] = (short)f2b(a.y);
    o[2] = (short)f2b(a.z); o[3] = (short)f2b(a.w);
    o[4] = (short)f2b(b.x); o[5] = (short)f2b(b.y);
    o[6] = (short)f2b(b.z); o[7] = (short)f2b(b.w);
    *(bf16x8*)(xb + base) = o;
}

// ---------------------------------------------------------------------------
// P1: pack + transpose Wq/Wkv to WallT[e][col 0..191][k 0..1023] bf16
// ---------------------------------------------------------------------------
__global__ __launch_bounds__(256) void wcvt_kernel(const float* __restrict__ Wq,
        const float* __restrict__ Wkv, short* __restrict__ WallT) {
    __shared__ float tile[32][33];
    int e = blockIdx.z;
    int c0 = blockIdx.x * 32;
    int d0 = blockIdx.y * 32;
    int t = threadIdx.x;
#pragma unroll
    for (int i = 0; i < 4; ++i) {
        int idx = t + i * 256;
        int d = idx >> 5, c = idx & 31;
        float v;
        if (c0 < 64)
            v = Wq[((size_t)e * DD + d0 + d) * HDD + c0 + c];
        else
            v = Wkv[((size_t)e * DD + d0 + d) * 2 * HDD + (c0 - 64 + c)];
        tile[d][c] = v;
    }
    __syncthreads();
#pragma unroll
    for (int i = 0; i < 4; ++i) {
        int idx = t + i * 256;
        int cr = idx >> 5, d2 = idx & 31;
        WallT[((size_t)e * 192 + c0 + cr) * DD + d0 + d2] = (short)f2b(tile[d2][cr]);
    }
}

// ---------------------------------------------------------------------------
// P2: transpose Wff[e][h][d] -> WffT[e][d][h] bf16. grid (32, 2, 16).
// ---------------------------------------------------------------------------
__global__ __launch_bounds__(256) void wfcvt_kernel(const float* __restrict__ Wff,
        short* __restrict__ WffT) {
    __shared__ float tile[32][33];
    int e = blockIdx.z;
    int d0 = blockIdx.x * 32;
    int h0 = blockIdx.y * 32;
    int t = threadIdx.x;
#pragma unroll
    for (int i = 0; i < 4; ++i) {
        int idx = t + i * 256;
        int h = idx >> 5, d = idx & 31;
        tile[h][d] = Wff[((size_t)e * HDD + h0 + h) * DD + d0 + d];
    }
    __syncthreads();
#pragma unroll
    for (int i = 0; i < 4; ++i) {
        int idx = t + i * 256;
        int d2 = idx >> 5, h2 = idx & 31;
        WffT[((size_t)e * DD + d0 + d2) * HDD + h0 + h2] = (short)f2b(tile[h2][d2]);
    }
}

// ---------------------------------------------------------------------------
// K1: gating
// ---------------------------------------------------------------------------
__global__ __launch_bounds__(256) void gate_kernel(const float* __restrict__ x,
        const float* __restrict__ wg, const float* __restrict__ bg,
        float* __restrict__ gate) {
    int token = blockIdx.x * 4 + (threadIdx.x >> 6);
    int lane = threadIdx.x & 63;
    const float* xr = x + (size_t)token * DD;
    float acc[EE];
#pragma unroll
    for (int e = 0; e < EE; ++e) acc[e] = 0.0f;
    for (int d = lane; d < DD; d += 64) {
        float xv = xr[d];
        const float4* wr = (const float4*)(wg + (size_t)d * EE);
        float4 w0 = wr[0], w1 = wr[1], w2 = wr[2], w3 = wr[3];
        acc[0]  = fmaf(xv, w0.x, acc[0]);  acc[1]  = fmaf(xv, w0.y, acc[1]);
        acc[2]  = fmaf(xv, w0.z, acc[2]);  acc[3]  = fmaf(xv, w0.w, acc[3]);
        acc[4]  = fmaf(xv, w1.x, acc[4]);  acc[5]  = fmaf(xv, w1.y, acc[5]);
        acc[6]  = fmaf(xv, w1.z, acc[6]);  acc[7]  = fmaf(xv, w1.w, acc[7]);
        acc[8]  = fmaf(xv, w2.x, acc[8]);  acc[9]  = fmaf(xv, w2.y, acc[9]);
        acc[10] = fmaf(xv, w2.z, acc[10]); acc[11] = fmaf(xv, w2.w, acc[11]);
        acc[12] = fmaf(xv, w3.x, acc[12]); acc[13] = fmaf(xv, w3.y, acc[13]);
        acc[14] = fmaf(xv, w3.z, acc[14]); acc[15] = fmaf(xv, w3.w, acc[15]);
    }
#pragma unroll
    for (int e = 0; e < EE; ++e) {
        float v = acc[e];
#pragma unroll
        for (int off = 32; off > 0; off >>= 1) v += __shfl_xor(v, off, 64);
        acc[e] = v + bg[e];
    }
    float mx = acc[0];
#pragma unroll
    for (int e = 1; e < EE; ++e) mx = fmaxf(mx, acc[e]);
    float sum = 0.0f;
#pragma unroll
    for (int e = 0; e < EE; ++e) { acc[e] = expf(acc[e] - mx); sum += acc[e]; }
    float inv = 1.0f / sum;
#pragma unroll
    for (int e = 0; e < EE; ++e) acc[e] *= inv;
    if (lane == 0) {
#pragma unroll
        for (int e = 0; e < EE; ++e) {
            int rank = 0;
#pragma unroll
            for (int j = 0; j < EE; ++j)
                rank += (acc[j] > acc[e]) || (acc[j] == acc[e] && j < e);
            gate[(size_t)token * EE + e] = (rank < TOPKK) ? acc[e] : 0.0f;
        }
    }
}

// ---------------------------------------------------------------------------
// K2: route (in place)
// ---------------------------------------------------------------------------
__global__ void route_kernel(float* __restrict__ gate) {
    int i = blockIdx.x * blockDim.x + threadIdx.x;
    if (i >= SS * EE) return;
    float m0 = gate[i];
    float m1 = gate[SS * EE + i];
    float den = m0 + m1 + 1e-6f;
    gate[i]           = m0 / den * 2.0f;
    gate[SS * EE + i] = m1 / den * 2.0f;
}

// ---------------------------------------------------------------------------
// K3a: rank of each token per (e,b). grid (8, 32), block 256.
// ---------------------------------------------------------------------------
__global__ __launch_bounds__(256) void rank_kernel(const float* __restrict__ gate,
        int* __restrict__ ranks) {
    __shared__ float vals[SS];
    int eb = blockIdx.y;
    int e = eb >> 1, b = eb & 1;
    int t = threadIdx.x;
    for (int s = t; s < SS; s += 256)
        vals[s] = gate[((size_t)b * SS + s) * EE + e];
    __syncthreads();
    int i = blockIdx.x * 256 + t;
    float vi = vals[i];
    int r = 0;
    for (int j = 0; j < SS; j += 4) {
        float4 vj = *(const float4*)&vals[j];
        r += (int)((vj.x > vi) | ((vj.x == vi) & (j + 0 < i)));
        r += (int)((vj.y > vi) | ((vj.y == vi) & (j + 1 < i)));
        r += (int)((vj.z > vi) | ((vj.z == vi) & (j + 2 < i)));
        r += (int)((vj.w > vi) | ((vj.w == vi) & (j + 3 < i)));
    }
    ranks[(size_t)eb * SS + i] = r;
}

// ---------------------------------------------------------------------------
// K3b: prefix-scan of selected flags -> seq_ids (ascending) + inv_slot
// ---------------------------------------------------------------------------
__global__ __launch_bounds__(1024) void scan_kernel(const int* __restrict__ ranks,
        int* __restrict__ seq_ids, int* __restrict__ inv_slot) {
    __shared__ int wsum[16];
    int eb = blockIdx.x;
    int e = eb >> 1, b = eb & 1;
    int t = threadIdx.x;
    int i0 = t * 2;
    int r0 = ranks[(size_t)eb * SS + i0];
    int r1 = ranks[(size_t)eb * SS + i0 + 1];
    int s0 = (r0 < CAPP), s1 = (r1 < CAPP);
    int cnt = s0 + s1;
    int lane = t & 63, wid = t >> 6;
    int incl = cnt;
#pragma unroll
    for (int off = 1; off < 64; off <<= 1) {
        int n = __shfl_up(incl, off, 64);
        if (lane >= off) incl += n;
    }
    if (lane == 63) wsum[wid] = incl;
    __syncthreads();
    int base = 0;
    for (int w = 0; w < wid; ++w) base += wsum[w];
    int pos = base + incl - cnt;
    if (s0) {
        seq_ids[(size_t)eb * CAPP + pos] = i0;
        inv_slot[((size_t)b * SS + i0) * EE + e] = pos;
        ++pos;
    }
    if (s1) {
        seq_ids[(size_t)eb * CAPP + pos] = i0 + 1;
        inv_slot[((size_t)b * SS + i0 + 1) * EE + e] = pos;
    }
}

// ---------------------------------------------------------------------------
// K4: q/k/v projection — bf16 MFMA, LDS-free, RoPE fused.
// ---------------------------------------------------------------------------
__global__ __launch_bounds__(256) void proj_kernel(const short* __restrict__ xb,
        const short* __restrict__ WallT, const int* __restrict__ seq_ids,
        short* __restrict__ qo, short* __restrict__ ko, short* __restrict__ vo) {
    __shared__ int sids[64];
    int eb = blockIdx.y;
    int e = eb >> 1, b = eb & 1;
    int m0 = blockIdx.x * 64;
    int t = threadIdx.x;
    int w = t >> 6, l = t & 63, lq = l >> 4, lr = l & 15;
    if (t < 64) sids[t] = seq_ids[(size_t)eb * CAPP + m0 + t];
    __syncthreads();
    const short* xrow = xb + (size_t)(b * SS + sids[w * 16 + lr]) * DD + lq * 8;
    const short* wTl = WallT + (size_t)e * 192 * DD + (size_t)lr * DD + lq * 8;
    f32x4 acc[12];
#pragma unroll
    for (int cb = 0; cb < 12; ++cb) acc[cb] = (f32x4){0.f, 0.f, 0.f, 0.f};
#pragma unroll 2
    for (int k0 = 0; k0 < DD; k0 += 32) {
        bf16x8 a = *(const bf16x8*)(xrow + k0);
#pragma unroll
        for (int cb = 0; cb < 12; ++cb) {
            bf16x8 bw = *(const bf16x8*)(wTl + (size_t)cb * 16 * DD + k0);
            acc[cb] = __builtin_amdgcn_mfma_f32_16x16x32_bf16(a, bw, acc[cb], 0, 0, 0);
        }
    }
    float f0 = exp2f(-(float)lr * 0.41524101186092029f);
    float f1 = exp2f(-(float)(16 + lr) * 0.41524101186092029f);
#pragma unroll
    for (int r = 0; r < 4; ++r) {
        int rrow = w * 16 + lq * 4 + r;
        float p = (float)sids[rrow];
        float s0, c0, s1, c1;
        sincosf(p * f0, &s0, &c0);
        sincosf(p * f1, &s1, &c1);
        size_t obase = ((size_t)eb * CAPP + m0 + rrow) * HDD;
        float q0 = acc[0][r] * c0 - acc[2][r] * s0;
        float q2 = acc[2][r] * c0 + acc[0][r] * s0;
        float q1 = acc[1][r] * c1 - acc[3][r] * s1;
        float q3 = acc[3][r] * c1 + acc[1][r] * s1;
        qo[obase + lr]      = (short)f2b(q0);
        qo[obase + 16 + lr] = (short)f2b(q1);
        qo[obase + 32 + lr] = (short)f2b(q2);
        qo[obase + 48 + lr] = (short)f2b(q3);
        float k0v = acc[4][r] * c0 - acc[6][r] * s0;
        float k2v = acc[6][r] * c0 + acc[4][r] * s0;
        float k1v = acc[5][r] * c1 - acc[7][r] * s1;
        float k3v = acc[7][r] * c1 + acc[5][r] * s1;
        ko[obase + lr]      = (short)f2b(k0v);
        ko[obase + 16 + lr] = (short)f2b(k1v);
        ko[obase + 32 + lr] = (short)f2b(k2v);
        ko[obase + 48 + lr] = (short)f2b(k3v);
#pragma unroll
        for (int u = 0; u < 4; ++u)
            vo[obase + u * 16 + lr] = (short)f2b(acc[8 + u][r]);
    }
}

// ---------------------------------------------------------------------------
// K6: causal flash attention, bf16 MFMA; ctx written bf16.
// ---------------------------------------------------------------------------
__global__ __launch_bounds__(256) void attn_kernel(const short* __restrict__ qi,
        const short* __restrict__ ki, const short* __restrict__ vi,
        short* __restrict__ ctxb) {
    __shared__ __align__(16) short Ks[64][72];
    __shared__ __align__(16) short Vt[64][72];
    __shared__ __align__(16) short Pl[4][16][72];
    int eb = blockIdx.x;
    int qt = 19 - blockIdx.y;
    int qrow0 = qt * 64;
    int t = threadIdx.x;
    int w = t >> 6, l = t & 63;
    int lq = l >> 4, lr = l & 15;
    const short* qb = qi + (size_t)eb * CAPP * HDD;
    const short* kb = ki + (size_t)eb * CAPP * HDD;
    const short* vb = vi + (size_t)eb * CAPP * HDD;

    const short* qrow = qb + (size_t)(qrow0 + w * 16 + lr) * HDD + lq * 8;
    bf16x8 aq[2];
    aq[0] = *(const bf16x8*)qrow;
    aq[1] = *(const bf16x8*)(qrow + 32);

    f32x4 O[4];
    float m_run[4], l_run[4];
#pragma unroll
    for (int cb = 0; cb < 4; ++cb) O[cb] = (f32x4){0.f, 0.f, 0.f, 0.f};
#pragma unroll
    for (int r = 0; r < 4; ++r) { m_run[r] = -INFINITY; l_run[r] = 0.0f; }

    int srow = t >> 2, scol = (t & 3) * 16;
    for (int kt = 0; kt <= qt; ++kt) {
        int krow0 = kt * 64;
        __syncthreads();
        const short* kg = kb + (size_t)(krow0 + srow) * HDD + scol;
        const short* vg = vb + (size_t)(krow0 + srow) * HDD + scol;
        bf16x8 kv0 = *(const bf16x8*)kg;
        bf16x8 kv1 = *(const bf16x8*)(kg + 8);
        bf16x8 vv0 = *(const bf16x8*)vg;
        bf16x8 vv1 = *(const bf16x8*)(vg + 8);
        *(bf16x8*)&Ks[srow][scol] = kv0;
        *(bf16x8*)&Ks[srow][scol + 8] = kv1;
#pragma unroll
        for (int u = 0; u < 8; ++u) {
            Vt[scol + u][srow] = vv0[u];
            Vt[scol + 8 + u][srow] = vv1[u];
        }
        __syncthreads();

        f32x4 S[4];
#pragma unroll
        for (int cb = 0; cb < 4; ++cb) {
            bf16x8 bk0 = *(const bf16x8*)&Ks[cb * 16 + lr][lq * 8];
            bf16x8 bk1 = *(const bf16x8*)&Ks[cb * 16 + lr][32 + lq * 8];
            f32x4 z = (f32x4){0.f, 0.f, 0.f, 0.f};
            z = __builtin_amdgcn_mfma_f32_16x16x32_bf16(aq[0], bk0, z, 0, 0, 0);
            S[cb] = __builtin_amdgcn_mfma_f32_16x16x32_bf16(aq[1], bk1, z, 0, 0, 0);
        }
        if (kt == qt) {
#pragma unroll
            for (int cb = 0; cb < 4; ++cb)
#pragma unroll
                for (int r = 0; r < 4; ++r) {
                    float val = S[cb][r] * 0.125f;
                    if (cb * 16 + lr > w * 16 + lq * 4 + r) val = -INFINITY;
                    S[cb][r] = val;
                }
        } else {
#pragma unroll
            for (int cb = 0; cb < 4; ++cb)
#pragma unroll
                for (int r = 0; r < 4; ++r) S[cb][r] *= 0.125f;
        }
        float p[4][4];
#pragma unroll
        for (int r = 0; r < 4; ++r) {
            float tm = fmaxf(fmaxf(S[0][r], S[1][r]), fmaxf(S[2][r], S[3][r]));
#pragma unroll
            for (int off = 1; off < 16; off <<= 1) tm = fmaxf(tm, __shfl_xor(tm, off, 64));
            float mnew = fmaxf(m_run[r], tm);
            float fac = expf(m_run[r] - mnew);
            m_run[r] = mnew;
            float rs = 0.0f;
#pragma unroll
            for (int cb = 0; cb < 4; ++cb) {
                p[cb][r] = expf(S[cb][r] - mnew);
                rs += p[cb][r];
            }
#pragma unroll
            for (int off = 1; off < 16; off <<= 1) rs += __shfl_xor(rs, off, 64);
            l_run[r] = l_run[r] * fac + rs;
            O[0][r] *= fac; O[1][r] *= fac; O[2][r] *= fac; O[3][r] *= fac;
        }
#pragma unroll
        for (int cb = 0; cb < 4; ++cb)
#pragma unroll
            for (int r = 0; r < 4; ++r)
                Pl[w][lq * 4 + r][cb * 16 + lr] = (short)f2b(p[cb][r]);
        bf16x8 ap0 = *(const bf16x8*)&Pl[w][lr][lq * 8];
        bf16x8 ap1 = *(const bf16x8*)&Pl[w][lr][32 + lq * 8];
#pragma unroll
        for (int cb = 0; cb < 4; ++cb) {
            bf16x8 bv0 = *(const bf16x8*)&Vt[cb * 16 + lr][lq * 8];
            bf16x8 bv1 = *(const bf16x8*)&Vt[cb * 16 + lr][32 + lq * 8];
            O[cb] = __builtin_amdgcn_mfma_f32_16x16x32_bf16(ap0, bv0, O[cb], 0, 0, 0);
            O[cb] = __builtin_amdgcn_mfma_f32_16x16x32_bf16(ap1, bv1, O[cb], 0, 0, 0);
        }
    }
    float invl[4];
#pragma unroll
    for (int r = 0; r < 4; ++r) invl[r] = 1.0f / l_run[r];
    short* cbase = ctxb + ((size_t)eb * CAPP + qrow0 + w * 16 + lq * 4) * HDD;
#pragma unroll
    for (int r = 0; r < 4; ++r)
#pragma unroll
        for (int cb = 0; cb < 4; ++cb)
            cbase[(size_t)r * HDD + cb * 16 + lr] = (short)f2b(O[cb][r] * invl[r]);
}

// ---------------------------------------------------------------------------
// K7: token-major combine — bf16 MFMA, no atomics.
// grid (B*S/64 = 64, D/256 = 4), block 256 = 4 waves.
// wave w owns cols [n0+w*64, +64). A = weighted ctx rows staged bf16 in LDS.
// ---------------------------------------------------------------------------
__global__ __launch_bounds__(256) void combine_kernel(const short* __restrict__ ctxb,
        const short* __restrict__ WffT, const float* __restrict__ bff,
        const int* __restrict__ inv_slot, const float* __restrict__ gate,
        float* __restrict__ combined) {
    __shared__ __align__(16) short Ab[64][72];
    __shared__ int slotL[64];
    __shared__ float wL[64];
    __shared__ float wsumL[64];
    int tb = blockIdx.x * 64;
    int b = tb / SS;
    int n0 = blockIdx.y * 256;
    int t = threadIdx.x;
    int w = t >> 6, l = t & 63, lq = l >> 4, lr = l & 15;
    if (t < 64) wsumL[t] = 0.0f;
    f32x4 acc[4][4];
#pragma unroll
    for (int m = 0; m < 4; ++m)
#pragma unroll
        for (int nb = 0; nb < 4; ++nb) acc[m][nb] = (f32x4){0.f, 0.f, 0.f, 0.f};

    int sr = t >> 2, sc = (t & 3) * 16;          // staging: row, col-chunk
    for (int e = 0; e < EE; ++e) {
        __syncthreads();                          // Ab/wL reuse safe
        if (t < 64) {
            int slot = inv_slot[(size_t)(tb + t) * EE + e];
            slotL[t] = slot;
            float wv = (slot >= 0) ? gate[(size_t)(tb + t) * EE + e] : 0.0f;
            wL[t] = wv;
            wsumL[t] += wv;
        }
        __syncthreads();
        {
            int slot = slotL[sr];
            float wv = wL[sr];
            bf16x8 i0 = (bf16x8){0,0,0,0,0,0,0,0}, i1 = i0;
            if (slot >= 0) {
                const short* crow = ctxb + ((size_t)(e * BB + b) * CAPP + slot) * HDD + sc;
                i0 = *(const bf16x8*)crow;
                i1 = *(const bf16x8*)(crow + 8);
            }
            bf16x8 o0, o1;
#pragma unroll
            for (int u = 0; u < 8; ++u) {
                o0[u] = (short)f2b(b2f(i0[u]) * wv);
                o1[u] = (short)f2b(b2f(i1[u]) * wv);
            }
            *(bf16x8*)&Ab[sr][sc] = o0;
            *(bf16x8*)&Ab[sr][sc + 8] = o1;
        }
        __syncthreads();
        const short* bbase = WffT + ((size_t)e * DD + n0 + w * 64) * HDD;
        bf16x8 bfrag[4][2];
#pragma unroll
        for (int nb = 0; nb < 4; ++nb) {
            bfrag[nb][0] = *(const bf16x8*)(bbase + (size_t)(nb * 16 + lr) * HDD + lq * 8);
            bfrag[nb][1] = *(const bf16x8*)(bbase + (size_t)(nb * 16 + lr) * HDD + 32 + lq * 8);
        }
#pragma unroll
        for (int m = 0; m < 4; ++m) {
            bf16x8 a0 = *(const bf16x8*)&Ab[m * 16 + lr][lq * 8];
            bf16x8 a1 = *(const bf16x8*)&Ab[m * 16 + lr][32 + lq * 8];
#pragma unroll
            for (int nb = 0; nb < 4; ++nb) {
                acc[m][nb] = __builtin_amdgcn_mfma_f32_16x16x32_bf16(a0, bfrag[nb][0],
                                                                     acc[m][nb], 0, 0, 0);
                acc[m][nb] = __builtin_amdgcn_mfma_f32_16x16x32_bf16(a1, bfrag[nb][1],
                                                                     acc[m][nb], 0, 0, 0);
            }
        }
    }
#pragma unroll
    for (int m = 0; m < 4; ++m)
#pragma unroll
        for (int nb = 0; nb < 4; ++nb) {
            int col = n0 + w * 64 + nb * 16 + lr;
            float bv = bff[col];
#pragma unroll
            for (int r = 0; r < 4; ++r) {
                int row = m * 16 + lq * 4 + r;
                combined[(size_t)(tb + row) * DD + col] = acc[m][nb][r] + wsumL[row] * bv;
            }
        }
}

// ---------------------------------------------------------------------------
// K8: h = x + combined ; LayerNorm(D) -> out
// ---------------------------------------------------------------------------
__global__ __launch_bounds__(256) void ln_kernel(const float* __restrict__ x,
        const float* __restrict__ combined, const float* __restrict__ gamma,
        const float* __restrict__ beta, float* __restrict__ out) {
    __shared__ float rsum[4], rsq[4];
    int token = blockIdx.x;
    int t = threadIdx.x;
    const float4* xr = (const float4*)(x + (size_t)token * DD);
    const float4* cr = (const float4*)(combined + (size_t)token * DD);
    float4 xv = xr[t], cv = cr[t];
    float4 h = make_float4(xv.x + cv.x, xv.y + cv.y, xv.z + cv.z, xv.w + cv.w);
    float sum = h.x + h.y + h.z + h.w;
    float sq  = h.x * h.x + h.y * h.y + h.z * h.z + h.w * h.w;
    int lane = t & 63, wid = t >> 6;
#pragma unroll
    for (int off = 32; off > 0; off >>= 1) {
        sum += __shfl_xor(sum, off, 64);
        sq  += __shfl_xor(sq, off, 64);
    }
    if (lane == 0) { rsum[wid] = sum; rsq[wid] = sq; }
    __syncthreads();
    float ts = rsum[0] + rsum[1] + rsum[2] + rsum[3];
    float tq = rsq[0] + rsq[1] + rsq[2] + rsq[3];
    float mu = ts * (1.0f / DD);
    float var = tq * (1.0f / DD) - mu * mu;
    float inv = rsqrtf(var + 1e-5f);
    float4 g = ((const float4*)gamma)[t];
    float4 be = ((const float4*)beta)[t];
    float4 o;
    o.x = (h.x - mu) * inv * g.x + be.x;
    o.y = (h.y - mu) * inv * g.y + be.y;
    o.z = (h.z - mu) * inv * g.z + be.z;
    o.w = (h.w - mu) * inv * g.w + be.w;
    ((float4*)(out + (size_t)token * DD))[t] = o;
}

// ---------------------------------------------------------------------------
extern "C" void kernel_launch(void* const* d_in, const int* in_sizes, int n_in,
                              void* d_out, int out_size, void* d_ws, size_t ws_size,
                              hipStream_t stream) {
    const float* x        = (const float*)d_in[0];
    const float* w_gate   = (const float*)d_in[1];
    const float* b_gate   = (const float*)d_in[2];
    const float* Wq       = (const float*)d_in[3];
    const float* Wkv      = (const float*)d_in[4];
    const float* Wff      = (const float*)d_in[5];
    const float* bff      = (const float*)d_in[6];
    const float* ln_gamma = (const float*)d_in[7];
    const float* ln_beta  = (const float*)d_in[8];
    float* out = (float*)d_out;
    char* ws = (char*)d_ws;

    // workspace layout (bytes); total ~52.9 MB
    float* gate     = (float*)(ws + 0);           // B*S*E fp32        262144
    int*   seq_ids  = (int*)  (ws + 262144);      // E*B*CAP           163840
    int*   inv_slot = (int*)  (ws + 425984);      // B*S*E             262144
    int*   ranks    = (int*)  (ws + 688128);      // E*B*S             262144
    short* xb       = (short*)(ws + 950272);      // B*S*D bf16        8388608
    short* WallT    = (short*)(ws + 9338880);     // E*192*D bf16      6291456
    short* WffT     = (short*)(ws + 15630336);    // E*D*HD bf16       2097152
    short* qb       = (short*)(ws + 17727488);    // E*B*CAP*HD bf16   5242880
    short* kb       = (short*)(ws + 22970368);
    short* vb       = (short*)(ws + 28213248);
    short* ctxb     = (short*)(ws + 33456128);    // E*B*CAP*HD bf16   5242880
    float* combined = (float*)(ws + 38699008);    // B*S*D fp32        16777216

    hipMemsetAsync(inv_slot, 0xFF, (size_t)BB * SS * EE * sizeof(int), stream);

    xcvt_kernel<<<BB * SS * DD / 8 / 256, 256, 0, stream>>>(x, xb);
    wcvt_kernel<<<dim3(6, 32, EE), 256, 0, stream>>>(Wq, Wkv, WallT);
    wfcvt_kernel<<<dim3(32, 2, EE), 256, 0, stream>>>(Wff, WffT);
    gate_kernel<<<BB * SS / 4, 256, 0, stream>>>(x, w_gate, b_gate, gate);
    route_kernel<<<(SS * EE + 255) / 256, 256, 0, stream>>>(gate);
    rank_kernel<<<dim3(SS / 256, EE * BB), 256, 0, stream>>>(gate, ranks);
    scan_kernel<<<EE * BB, 1024, 0, stream>>>(ranks, seq_ids, inv_slot);
    proj_kernel<<<dim3(CAPP / 64, EE * BB), 256, 0, stream>>>(xb, WallT, seq_ids,
                                                              qb, kb, vb);
    attn_kernel<<<dim3(EE * BB, CAPP / 64), 256, 0, stream>>>(qb, kb, vb, ctxb);
    combine_kernel<<<dim3(BB * SS / 64, DD / 256), 256, 0, stream>>>(
        ctxb, WffT, bff, inv_slot, gate, combined);
    ln_kernel<<<BB * SS, 256, 0, stream>>>(x, combined, ln_gamma, ln_beta, out);
}